// Round 1
// baseline (3678.476 us; speedup 1.0000x reference)
//
#include <hip/hip_runtime.h>
#include <stdint.h>

// Problem constants (B=16, C=256, H=W=32, K=8192)
#define CCDIM 256
#define HWP 1024
#define NPOS 16384
#define KC 8192
#define KSPLIT 16
#define KPER (KC / KSPLIT) /* 512 codes per K-split block */
#define NCH 32             /* codes per accumulator chunk (acc VGPRs) */
#define CCH 32             /* dims per x-register chunk */

// ---------------------------------------------------------------------------
// Kernel 1: e2[k] = ||codebook[k]||^2. One wave per code, coalesced float4.
// ---------------------------------------------------------------------------
__global__ __launch_bounds__(256) void e2_kernel(const float* __restrict__ cb,
                                                 float* __restrict__ e2) {
  const int lane = threadIdx.x & 63;
  const int wid = threadIdx.x >> 6;
  const int code = blockIdx.x * 4 + wid;
  const float4 v = *(const float4*)(cb + (size_t)code * CCDIM + lane * 4);
  float s = v.x * v.x + v.y * v.y + v.z * v.z + v.w * v.w;
#pragma unroll
  for (int off = 32; off > 0; off >>= 1) s += __shfl_down(s, off, 64);
  if (lane == 0) e2[code] = s;
}

// ---------------------------------------------------------------------------
// Kernel 2: fused distance + partial argmin.
// lane <-> position (x in VGPRs, coalesced loads); codebook via wave-uniform
// scalar loads (SGPR operand of v_fmac). d = e2[k] - 2*dot (x2 constant per
// row, doesn't affect argmin). Strict < keeps lowest index (jnp.argmin).
// ---------------------------------------------------------------------------
__global__ __launch_bounds__(256, 4) void argmin_kernel(
    const float* __restrict__ x, const float* __restrict__ cb,
    const float* __restrict__ e2, float* __restrict__ pminv,
    int* __restrict__ pmini) {
  const int m = blockIdx.x * 256 + threadIdx.x;  // global position
  const int b = m >> 10;
  const int hw = m & 1023;
  const float* xp = x + (size_t)b * CCDIM * HWP + hw;
  const int kbase = blockIdx.y * KPER;
  float minv = __builtin_inff();
  int mini = 0;
#pragma unroll 1
  for (int nc = 0; nc < KPER; nc += NCH) {
    float acc[NCH];
#pragma unroll
    for (int j = 0; j < NCH; ++j) acc[j] = 0.0f;
#pragma unroll 1
    for (int cc0 = 0; cc0 < CCDIM; cc0 += CCH) {
      float xr[CCH];
#pragma unroll
      for (int c = 0; c < CCH; ++c) xr[c] = xp[(size_t)(cc0 + c) * HWP];
      const float* cbp = cb + (size_t)(kbase + nc) * CCDIM + cc0;
#pragma unroll
      for (int j = 0; j < NCH; ++j) {
#pragma unroll
        for (int c = 0; c < CCH; ++c)
          acc[j] = fmaf(xr[c], cbp[j * CCDIM + c], acc[j]);
      }
    }
#pragma unroll
    for (int j = 0; j < NCH; ++j) {
      const float d = fmaf(-2.0f, acc[j], e2[kbase + nc + j]);
      if (d < minv) {  // strict: first (lowest) index wins on ties
        minv = d;
        mini = kbase + nc + j;
      }
    }
  }
  pminv[(size_t)blockIdx.y * NPOS + m] = minv;
  pmini[(size_t)blockIdx.y * NPOS + m] = mini;
}

// ---------------------------------------------------------------------------
// Kernel 3: merge K-split partials (ascending split order + strict < keeps
// the lowest code index on exact ties).
// ---------------------------------------------------------------------------
__global__ __launch_bounds__(256) void merge_kernel(
    const float* __restrict__ pminv, const int* __restrict__ pmini,
    int* __restrict__ idx) {
  const int m = blockIdx.x * 256 + threadIdx.x;
  float mv = __builtin_inff();
  int mi = 0;
#pragma unroll
  for (int s = 0; s < KSPLIT; ++s) {
    const float v = pminv[(size_t)s * NPOS + m];
    const int i = pmini[(size_t)s * NPOS + m];
    if (v < mv) {
      mv = v;
      mi = i;
    }
  }
  idx[m] = mi;
}

// ---------------------------------------------------------------------------
// Kernel 4: gather q = codebook[idx], write out in [B,C,H,W] layout, and
// accumulate sum((q-x)^2). Rows staged coalesced into LDS (pad +1 -> the
// transposed reads are 2-way, i.e. free).
// ---------------------------------------------------------------------------
__global__ __launch_bounds__(256) void gather_kernel(
    const float* __restrict__ x, const float* __restrict__ cb,
    const int* __restrict__ idx, float* __restrict__ out,
    float* __restrict__ acc) {
  __shared__ float rows[64][CCDIM + 1];
  __shared__ float wsum[4];
  const int p0 = blockIdx.x * 64;  // 64 positions, all within one b
  const int lane = threadIdx.x & 63;
  const int wid = threadIdx.x >> 6;
#pragma unroll 1
  for (int r = wid * 16; r < wid * 16 + 16; ++r) {
    const int code = idx[p0 + r];
    const float4 v = *(const float4*)(cb + (size_t)code * CCDIM + lane * 4);
    rows[r][lane * 4 + 0] = v.x;
    rows[r][lane * 4 + 1] = v.y;
    rows[r][lane * 4 + 2] = v.z;
    rows[r][lane * 4 + 3] = v.w;
  }
  __syncthreads();
  const int b = p0 >> 10;
  const int hw0 = p0 & 1023;
  const size_t obase = (size_t)b * CCDIM * HWP + hw0 + lane;
  float lsum = 0.0f;
#pragma unroll 4
  for (int c = wid * 64; c < wid * 64 + 64; ++c) {
    const float q = rows[lane][c];
    const float xv = x[obase + (size_t)c * HWP];
    out[obase + (size_t)c * HWP] = q;
    const float dd = q - xv;
    lsum = fmaf(dd, dd, lsum);
  }
#pragma unroll
  for (int off = 32; off > 0; off >>= 1) lsum += __shfl_down(lsum, off, 64);
  if (lane == 0) wsum[wid] = lsum;
  __syncthreads();
  if (threadIdx.x == 0) atomicAdd(acc, wsum[0] + wsum[1] + wsum[2] + wsum[3]);
}

// ---------------------------------------------------------------------------
// Kernel 5: losses. codebook_loss == commitment_loss == mean((q-x)^2).
// ---------------------------------------------------------------------------
__global__ void finalize_kernel(const float* __restrict__ acc,
                                float* __restrict__ out) {
  const float mean = acc[0] * (1.0f / (float)((size_t)NPOS * CCDIM));
  out[(size_t)NPOS * CCDIM] = mean;
  out[(size_t)NPOS * CCDIM + 1] = mean;
}

extern "C" void kernel_launch(void* const* d_in, const int* in_sizes, int n_in,
                              void* d_out, int out_size, void* d_ws,
                              size_t ws_size, hipStream_t stream) {
  (void)in_sizes;
  (void)n_in;
  (void)out_size;
  (void)ws_size;
  const float* x = (const float*)d_in[0];
  const float* cb = (const float*)d_in[1];
  float* out = (float*)d_out;

  // Workspace layout (~2.2 MB total)
  float* e2 = (float*)d_ws;                  // KC floats
  float* pminv = e2 + KC;                    // KSPLIT*NPOS floats
  int* pmini = (int*)(pminv + KSPLIT * NPOS);  // KSPLIT*NPOS ints
  int* idx = pmini + (size_t)KSPLIT * NPOS;  // NPOS ints
  float* acc = (float*)(idx + NPOS);         // 1 float

  hipMemsetAsync(acc, 0, sizeof(float), stream);
  e2_kernel<<<KC / 4, 256, 0, stream>>>(cb, e2);
  argmin_kernel<<<dim3(NPOS / 256, KSPLIT), 256, 0, stream>>>(x, cb, e2, pminv,
                                                              pmini);
  merge_kernel<<<NPOS / 256, 256, 0, stream>>>(pminv, pmini, idx);
  gather_kernel<<<NPOS / 64, 256, 0, stream>>>(x, cb, idx, out, acc);
  finalize_kernel<<<1, 1, 0, stream>>>(acc, out);
}

// Round 2
// 371.530 us; speedup vs baseline: 9.9009x; 9.9009x over previous
//
#include <hip/hip_runtime.h>
#include <stdint.h>

// Problem constants (B=16, C=256, H=W=32, K=8192)
#define CCDIM 256
#define HWP 1024
#define NPOS 16384
#define KC 8192
#define NKB 64  // number of 128-code tiles (KC/128)

typedef unsigned short u16;
typedef unsigned int u32;
typedef __attribute__((ext_vector_type(8))) short short8;
typedef __attribute__((ext_vector_type(4))) float f32x4;

__device__ __forceinline__ u16 bf16_rne(float f) {
  u32 u = __float_as_uint(f);
  return (u16)((u + 0x7FFFu + ((u >> 16) & 1u)) >> 16);
}
__device__ __forceinline__ float bf16_f32(u16 h) {
  return __uint_as_float(((u32)h) << 16);
}

// global_load_lds, width 16: lane i -> ldsbase + i*16
#define GLD(g, l)                                                   \
  __builtin_amdgcn_global_load_lds(                                 \
      (const __attribute__((address_space(1))) u32*)(g),            \
      (__attribute__((address_space(3))) u32*)(l), 16, 0, 0)

// ---------------------------------------------------------------------------
// pack_x: x [B,C,HW] f32 -> xh/xl [NPOS][C] bf16 (hi + residual-lo), via LDS
// transpose (two 128-c halves to stay under the 64 KB static LDS limit).
// ---------------------------------------------------------------------------
__global__ __launch_bounds__(256) void pack_x(const float* __restrict__ x,
                                              u16* __restrict__ xh,
                                              u16* __restrict__ xl) {
  __shared__ float tile[64][129];
  const int t = threadIdx.x, lane = t & 63, w = t >> 6;
  const int b = blockIdx.x >> 4;
  const int hw0 = (blockIdx.x & 15) * 64;
  const int p0 = blockIdx.x * 64;  // = b*1024 + hw0
#pragma unroll 1
  for (int half = 0; half < 2; ++half) {
#pragma unroll 4
    for (int i = 0; i < 32; ++i) {
      const int c = half * 128 + w * 32 + i;
      tile[lane][c & 127] =
          x[(size_t)b * (CCDIM * HWP) + (size_t)c * HWP + hw0 + lane];
    }
    __syncthreads();
    const int r = t >> 2, q = t & 3;
#pragma unroll
    for (int j = 0; j < 4; ++j) {
      const int cl0 = (q + 4 * j) * 8;  // 0..127 within half
      u32 hw_[4], lw_[4];
#pragma unroll
      for (int p = 0; p < 4; ++p) {
        const float f0 = tile[r][cl0 + 2 * p];
        const float f1 = tile[r][cl0 + 2 * p + 1];
        const u16 h0 = bf16_rne(f0), h1 = bf16_rne(f1);
        const u16 l0 = bf16_rne(f0 - bf16_f32(h0));
        const u16 l1 = bf16_rne(f1 - bf16_f32(h1));
        hw_[p] = (u32)h0 | ((u32)h1 << 16);
        lw_[p] = (u32)l0 | ((u32)l1 << 16);
      }
      const size_t eo = (size_t)(p0 + r) * CCDIM + half * 128 + cl0;
      *(uint4*)(xh + eo) = make_uint4(hw_[0], hw_[1], hw_[2], hw_[3]);
      *(uint4*)(xl + eo) = make_uint4(lw_[0], lw_[1], lw_[2], lw_[3]);
    }
    __syncthreads();
  }
}

// ---------------------------------------------------------------------------
// pack_cb_e2: cb [K][C] f32 -> ch/cl bf16 pair + e2[k] = ||cb[k]||^2 (f32).
// One wave per code row.
// ---------------------------------------------------------------------------
__global__ __launch_bounds__(256) void pack_cb_e2(const float* __restrict__ cb,
                                                  u16* __restrict__ ch,
                                                  u16* __restrict__ cl,
                                                  float* __restrict__ e2) {
  const int lane = threadIdx.x & 63, w = threadIdx.x >> 6;
  const int k = blockIdx.x * 4 + w;
  const float4 v = *(const float4*)(cb + (size_t)k * CCDIM + lane * 4);
  float s = v.x * v.x + v.y * v.y + v.z * v.z + v.w * v.w;
  const float f[4] = {v.x, v.y, v.z, v.w};
  u32 hwd[2], lwd[2];
#pragma unroll
  for (int p = 0; p < 2; ++p) {
    const u16 h0 = bf16_rne(f[2 * p]), h1 = bf16_rne(f[2 * p + 1]);
    const u16 l0 = bf16_rne(f[2 * p] - bf16_f32(h0));
    const u16 l1 = bf16_rne(f[2 * p + 1] - bf16_f32(h1));
    hwd[p] = (u32)h0 | ((u32)h1 << 16);
    lwd[p] = (u32)l0 | ((u32)l1 << 16);
  }
  const size_t eo = (size_t)k * CCDIM + lane * 4;
  *(uint2*)(ch + eo) = make_uint2(hwd[0], hwd[1]);
  *(uint2*)(cl + eo) = make_uint2(lwd[0], lwd[1]);
#pragma unroll
  for (int off = 32; off > 0; off >>= 1) s += __shfl_down(s, off, 64);
  if (lane == 0) e2[k] = s;
}

// ---------------------------------------------------------------------------
// gemm_argmin: 128(pos) x 128(code) tile, BK=32, split-bf16 (3 MFMAs per
// fragment pair). XOR-swizzled LDS so ds_read_b128 fragment reads are
// conflict-free while global_load_lds stays contiguous-per-lane. Fused
// epilogue: d = e2 - 2*dot, per-tile argmin -> pminv/pmini[kb][pos].
// ---------------------------------------------------------------------------
#define LDS_US (4 * 128 * 32) /* 4 buffers: A_h, A_l, B_h, B_l (8 KB each) */

__global__ __launch_bounds__(256, 3) void gemm_argmin(
    const u16* __restrict__ xh, const u16* __restrict__ xl,
    const u16* __restrict__ ch, const u16* __restrict__ cl,
    const float* __restrict__ e2, float* __restrict__ pminv,
    int* __restrict__ pmini) {
  __shared__ __align__(16) u16 lds[LDS_US];
  const int tid = threadIdx.x;
  const int w = tid >> 6, lane = tid & 63;
  const int fr = lane & 15, qg = lane >> 4;
  const int m0 = blockIdx.x * 128, n0 = blockIdx.y * 128;
  const int m_off = (w & 1) * 64, n_off = (w >> 1) * 64;

  f32x4 acc[4][4];
#pragma unroll
  for (int i = 0; i < 4; ++i)
#pragma unroll
    for (int j = 0; j < 4; ++j) acc[i][j] = (f32x4){0.f, 0.f, 0.f, 0.f};

  // staging: wave covers slots [w*128, w*128+128); slot s -> row s>>2,
  // swizzled chunk (s&3)^((row>>1)&3); lane lands at ldsbase + lane*16.
  const int s0 = w * 128 + lane, s1 = s0 + 64;
  const int r0 = s0 >> 2, g0 = (s0 & 3) ^ ((r0 >> 1) & 3);
  const int r1 = s1 >> 2, g1 = (s1 & 3) ^ ((r1 >> 1) & 3);
  const size_t offA0 = (size_t)(m0 + r0) * CCDIM + g0 * 8;
  const size_t offA1 = (size_t)(m0 + r1) * CCDIM + g1 * 8;
  const size_t offB0 = (size_t)(n0 + r0) * CCDIM + g0 * 8;
  const size_t offB1 = (size_t)(n0 + r1) * CCDIM + g1 * 8;
  const int lb0 = (w * 128) * 8;       // u16 index of wave slot base (t=0)
  const int lb1 = (w * 128 + 64) * 8;  // t=1

#pragma unroll 1
  for (int kt = 0; kt < 8; ++kt) {
    const int c0 = kt * 32;
    GLD(xh + offA0 + c0, &lds[0 * 4096 + lb0]);
    GLD(xh + offA1 + c0, &lds[0 * 4096 + lb1]);
    GLD(xl + offA0 + c0, &lds[1 * 4096 + lb0]);
    GLD(xl + offA1 + c0, &lds[1 * 4096 + lb1]);
    GLD(ch + offB0 + c0, &lds[2 * 4096 + lb0]);
    GLD(ch + offB1 + c0, &lds[2 * 4096 + lb1]);
    GLD(cl + offB0 + c0, &lds[3 * 4096 + lb0]);
    GLD(cl + offB1 + c0, &lds[3 * 4096 + lb1]);
    __syncthreads();

    short8 ah[4], al[4];
#pragma unroll
    for (int mf = 0; mf < 4; ++mf) {
      const int rl = m_off + mf * 16 + fr;
      const int sw = (qg ^ ((rl >> 1) & 3)) * 8;
      ah[mf] = *(const short8*)&lds[0 * 4096 + rl * 32 + sw];
      al[mf] = *(const short8*)&lds[1 * 4096 + rl * 32 + sw];
    }
#pragma unroll
    for (int nf = 0; nf < 4; ++nf) {
      const int rl = n_off + nf * 16 + fr;
      const int sw = (qg ^ ((rl >> 1) & 3)) * 8;
      const short8 bh = *(const short8*)&lds[2 * 4096 + rl * 32 + sw];
      const short8 bl = *(const short8*)&lds[3 * 4096 + rl * 32 + sw];
#pragma unroll
      for (int mf = 0; mf < 4; ++mf) {
        acc[mf][nf] = __builtin_amdgcn_mfma_f32_16x16x32_bf16(ah[mf], bh,
                                                              acc[mf][nf], 0, 0, 0);
        acc[mf][nf] = __builtin_amdgcn_mfma_f32_16x16x32_bf16(ah[mf], bl,
                                                              acc[mf][nf], 0, 0, 0);
        acc[mf][nf] = __builtin_amdgcn_mfma_f32_16x16x32_bf16(al[mf], bh,
                                                              acc[mf][nf], 0, 0, 0);
      }
    }
    __syncthreads();
  }

  // Epilogue. C/D layout: col = lane&15, row = (lane>>4)*4 + reg.
  float e2v[4];
  int cidx[4];
#pragma unroll
  for (int nf = 0; nf < 4; ++nf) {
    cidx[nf] = n0 + n_off + nf * 16 + fr;
    e2v[nf] = e2[cidx[nf]];
  }
  float dmin[4][4];
  int didx[4][4];
#pragma unroll
  for (int mf = 0; mf < 4; ++mf)
#pragma unroll
    for (int r = 0; r < 4; ++r) {
      float bv = fmaf(-2.0f, acc[mf][0][r], e2v[0]);
      int bi = cidx[0];
#pragma unroll
      for (int nf = 1; nf < 4; ++nf) {
        const float d = fmaf(-2.0f, acc[mf][nf][r], e2v[nf]);
        if (d < bv) { bv = d; bi = cidx[nf]; }  // ascending cols: strict <
      }
      dmin[mf][r] = bv;
      didx[mf][r] = bi;
    }
  // reduce across the 16 lanes sharing a row (lane bits 0-3 = col)
#pragma unroll
  for (int mask = 1; mask <= 8; mask <<= 1) {
#pragma unroll
    for (int mf = 0; mf < 4; ++mf)
#pragma unroll
      for (int r = 0; r < 4; ++r) {
        const float vo = __shfl_xor(dmin[mf][r], mask, 64);
        const int io = __shfl_xor(didx[mf][r], mask, 64);
        if (vo < dmin[mf][r] || (vo == dmin[mf][r] && io < didx[mf][r])) {
          dmin[mf][r] = vo;
          didx[mf][r] = io;
        }
      }
  }
  // combine the two waves sharing rows (n_off 0 vs 64) via LDS
  float* sv = (float*)lds;
  int* si = (int*)(lds + 8192);
  if (fr == 0 && n_off == 64) {
#pragma unroll
    for (int mf = 0; mf < 4; ++mf)
#pragma unroll
      for (int r = 0; r < 4; ++r) {
        const int rl = m_off + mf * 16 + qg * 4 + r;
        sv[rl] = dmin[mf][r];
        si[rl] = didx[mf][r];
      }
  }
  __syncthreads();
  if (fr == 0 && n_off == 0) {
#pragma unroll
    for (int mf = 0; mf < 4; ++mf)
#pragma unroll
      for (int r = 0; r < 4; ++r) {
        const int rl = m_off + mf * 16 + qg * 4 + r;
        float v = dmin[mf][r];
        int i = didx[mf][r];
        const float vo = sv[rl];
        const int io = si[rl];
        if (vo < v || (vo == v && io < i)) { v = vo; i = io; }
        pminv[(size_t)blockIdx.y * NPOS + m0 + rl] = v;
        pmini[(size_t)blockIdx.y * NPOS + m0 + rl] = i;
      }
  }
}

// ---------------------------------------------------------------------------
// merge_refine: per position scan 64 tile-partials keeping top-3 candidates,
// recompute their distances exactly in f32 (x2 term cancels), pick min with
// lowest-index tie-break. One thread per position (x reads coalesced).
// ---------------------------------------------------------------------------
__global__ __launch_bounds__(64) void merge_refine(
    const float* __restrict__ pminv, const int* __restrict__ pmini,
    const float* __restrict__ x, const float* __restrict__ cb,
    const float* __restrict__ e2, int* __restrict__ idx) {
  const int m = blockIdx.x * 64 + threadIdx.x;
  float v1 = __builtin_inff(), v2 = v1, v3 = v1;
  int i1 = 0, i2 = 0, i3 = 0;
#pragma unroll 4
  for (int kb = 0; kb < NKB; ++kb) {
    const float v = pminv[(size_t)kb * NPOS + m];
    const int i = pmini[(size_t)kb * NPOS + m];
    if (v < v1 || (v == v1 && i < i1)) {
      v3 = v2; i3 = i2; v2 = v1; i2 = i1; v1 = v; i1 = i;
    } else if (v < v2 || (v == v2 && i < i2)) {
      v3 = v2; i3 = i2; v2 = v; i2 = i;
    } else if (v < v3 || (v == v3 && i < i3)) {
      v3 = v; i3 = i;
    }
  }
  const float* xp = x + (size_t)(m >> 10) * (CCDIM * HWP) + (m & 1023);
  const float* c1 = cb + (size_t)i1 * CCDIM;
  const float* c2 = cb + (size_t)i2 * CCDIM;
  const float* c3 = cb + (size_t)i3 * CCDIM;
  float d1 = 0.f, d2 = 0.f, d3 = 0.f;
#pragma unroll 8
  for (int c = 0; c < CCDIM; ++c) {
    const float xv = xp[(size_t)c * HWP];
    d1 = fmaf(xv, c1[c], d1);
    d2 = fmaf(xv, c2[c], d2);
    d3 = fmaf(xv, c3[c], d3);
  }
  const float dd1 = fmaf(-2.f, d1, e2[i1]);
  const float dd2 = fmaf(-2.f, d2, e2[i2]);
  const float dd3 = fmaf(-2.f, d3, e2[i3]);
  float bv = dd1;
  int bi = i1;
  if (dd2 < bv || (dd2 == bv && i2 < bi)) { bv = dd2; bi = i2; }
  if (dd3 < bv || (dd3 == bv && i3 < bi)) { bv = dd3; bi = i3; }
  idx[m] = bi;
}

// ---------------------------------------------------------------------------
// gather: q = codebook[idx] -> out in [B,C,H,W], fused sum((q-x)^2).
// ---------------------------------------------------------------------------
__global__ __launch_bounds__(256) void gather_kernel(
    const float* __restrict__ x, const float* __restrict__ cb,
    const int* __restrict__ idx, float* __restrict__ out,
    float* __restrict__ acc) {
  __shared__ float rows[64][CCDIM + 1];
  __shared__ float wsum[4];
  const int p0 = blockIdx.x * 64;
  const int lane = threadIdx.x & 63;
  const int wid = threadIdx.x >> 6;
#pragma unroll 1
  for (int r = wid * 16; r < wid * 16 + 16; ++r) {
    const int code = idx[p0 + r];
    const float4 v = *(const float4*)(cb + (size_t)code * CCDIM + lane * 4);
    rows[r][lane * 4 + 0] = v.x;
    rows[r][lane * 4 + 1] = v.y;
    rows[r][lane * 4 + 2] = v.z;
    rows[r][lane * 4 + 3] = v.w;
  }
  __syncthreads();
  const int b = p0 >> 10;
  const int hw0 = p0 & 1023;
  const size_t obase = (size_t)b * (CCDIM * HWP) + hw0 + lane;
  float lsum = 0.0f;
#pragma unroll 4
  for (int c = wid * 64; c < wid * 64 + 64; ++c) {
    const float q = rows[lane][c];
    const float xv = x[obase + (size_t)c * HWP];
    out[obase + (size_t)c * HWP] = q;
    const float dd = q - xv;
    lsum = fmaf(dd, dd, lsum);
  }
#pragma unroll
  for (int off = 32; off > 0; off >>= 1) lsum += __shfl_down(lsum, off, 64);
  if (lane == 0) wsum[wid] = lsum;
  __syncthreads();
  if (threadIdx.x == 0) atomicAdd(acc, wsum[0] + wsum[1] + wsum[2] + wsum[3]);
}

__global__ void finalize_kernel(const float* __restrict__ acc,
                                float* __restrict__ out) {
  const float mean = acc[0] * (1.0f / (float)((size_t)NPOS * CCDIM));
  out[(size_t)NPOS * CCDIM] = mean;
  out[(size_t)NPOS * CCDIM + 1] = mean;
}

extern "C" void kernel_launch(void* const* d_in, const int* in_sizes, int n_in,
                              void* d_out, int out_size, void* d_ws,
                              size_t ws_size, hipStream_t stream) {
  (void)in_sizes;
  (void)n_in;
  (void)out_size;
  (void)ws_size;
  const float* x = (const float*)d_in[0];
  const float* cb = (const float*)d_in[1];
  float* out = (float*)d_out;

  // Workspace layout (34 MB total)
  uint8_t* ws = (uint8_t*)d_ws;
  float* e2 = (float*)(ws + 0);                       // 32 KB
  float* pminv = (float*)(ws + (1ull << 20));         // 4 MB
  int* pmini = (int*)(ws + (5ull << 20));             // 4 MB
  int* idx = (int*)(ws + (9ull << 20));               // 64 KB
  float* acc = (float*)(ws + (9ull << 20) + 65536);   // 4 B
  u16* xh = (u16*)(ws + (10ull << 20));               // 8 MB
  u16* xl = (u16*)(ws + (18ull << 20));               // 8 MB
  u16* ch = (u16*)(ws + (26ull << 20));               // 4 MB
  u16* cl = (u16*)(ws + (30ull << 20));               // 4 MB

  hipMemsetAsync(acc, 0, sizeof(float), stream);
  pack_x<<<NPOS / 64, 256, 0, stream>>>(x, xh, xl);
  pack_cb_e2<<<KC / 4, 256, 0, stream>>>(cb, ch, cl, e2);
  gemm_argmin<<<dim3(NPOS / 128, KC / 128), 256, 0, stream>>>(xh, xl, ch, cl,
                                                              e2, pminv, pmini);
  merge_refine<<<NPOS / 64, 64, 0, stream>>>(pminv, pmini, x, cb, e2, idx);
  gather_kernel<<<NPOS / 64, 256, 0, stream>>>(x, cb, idx, out, acc);
  finalize_kernel<<<1, 1, 0, stream>>>(acc, out);
}

// Round 3
// 221.686 us; speedup vs baseline: 16.5932x; 1.6759x over previous
//
#include <hip/hip_runtime.h>
#include <stdint.h>

// Problem constants (B=16, C=256, H=W=32, K=8192)
#define CCDIM 256
#define HWP 1024
#define NPOS 16384
#define KC 8192
#define NKB 64  // number of 128-code tiles

typedef unsigned short u16;
typedef unsigned int u32;
typedef unsigned long long u64;
typedef __attribute__((ext_vector_type(8))) _Float16 half8;
typedef __attribute__((ext_vector_type(4))) float f32x4;

__device__ __forceinline__ u16 f16bits(float f) {
  _Float16 h = (_Float16)f;  // RNE
  return *(u16*)&h;
}
__device__ __forceinline__ u32 umin2(u32 a, u32 b) { return a < b ? a : b; }
__device__ __forceinline__ u32 umax2(u32 a, u32 b) { return a > b ? a : b; }

// global_load_lds, width 16: lane i -> ldsbase + i*16
#define GLD(g, l)                                                   \
  __builtin_amdgcn_global_load_lds(                                 \
      (const __attribute__((address_space(1))) u32*)(g),            \
      (__attribute__((address_space(3))) u32*)(l), 16, 0, 0)

// ---------------------------------------------------------------------------
// pack_x: x [B,C,HW] f32 -> xh [NPOS][C] f16 via LDS transpose.
// ---------------------------------------------------------------------------
__global__ __launch_bounds__(256) void pack_x(const float* __restrict__ x,
                                              u16* __restrict__ xh) {
  __shared__ float tile[64][129];
  const int t = threadIdx.x, lane = t & 63, w = t >> 6;
  const int b = blockIdx.x >> 4;
  const int hw0 = (blockIdx.x & 15) * 64;
  const int p0 = blockIdx.x * 64;  // = b*1024 + hw0
#pragma unroll 1
  for (int half = 0; half < 2; ++half) {
#pragma unroll 4
    for (int i = 0; i < 32; ++i) {
      const int c = half * 128 + w * 32 + i;
      tile[lane][c & 127] =
          x[(size_t)b * (CCDIM * HWP) + (size_t)c * HWP + hw0 + lane];
    }
    __syncthreads();
    const int r = t >> 2, q = t & 3;
#pragma unroll
    for (int j = 0; j < 4; ++j) {
      const int cl0 = (q + 4 * j) * 8;
      u32 wd[4];
#pragma unroll
      for (int p = 0; p < 4; ++p)
        wd[p] = (u32)f16bits(tile[r][cl0 + 2 * p]) |
                ((u32)f16bits(tile[r][cl0 + 2 * p + 1]) << 16);
      *(uint4*)(xh + (size_t)(p0 + r) * CCDIM + half * 128 + cl0) =
          make_uint4(wd[0], wd[1], wd[2], wd[3]);
    }
    __syncthreads();
  }
}

// ---------------------------------------------------------------------------
// pack_cb_e2: cb [K][C] f32 -> ch f16 + e2[k] = ||cb[k]||^2 (f32).
// ---------------------------------------------------------------------------
__global__ __launch_bounds__(256) void pack_cb_e2(const float* __restrict__ cb,
                                                  u16* __restrict__ ch,
                                                  float* __restrict__ e2) {
  const int lane = threadIdx.x & 63, w = threadIdx.x >> 6;
  const int k = blockIdx.x * 4 + w;
  const float4 v = *(const float4*)(cb + (size_t)k * CCDIM + lane * 4);
  float s = v.x * v.x + v.y * v.y + v.z * v.z + v.w * v.w;
  const u32 w0 = (u32)f16bits(v.x) | ((u32)f16bits(v.y) << 16);
  const u32 w1 = (u32)f16bits(v.z) | ((u32)f16bits(v.w) << 16);
  *(uint2*)(ch + (size_t)k * CCDIM + lane * 4) = make_uint2(w0, w1);
#pragma unroll
  for (int off = 32; off > 0; off >>= 1) s += __shfl_down(s, off, 64);
  if (lane == 0) e2[k] = s;
}

// ---------------------------------------------------------------------------
// gemm_argmin: 128x128 tile, BK=32, single f16 MFMA per fragment pair.
// Selection keys: k = (u32)((d + 512)*256) << 13 | code_idx  (d = e2 - 2*dot;
// monotone, 0.004 resolution, lower idx wins ties). Epilogue keeps TOP-2 per
// tile per position -> part[kb][2][NPOS] (u32 keys).
// ---------------------------------------------------------------------------
#define LDS_US (2 * 128 * 32) /* A (xh) + B (ch), 8 KB each */

__global__ __launch_bounds__(256, 3) void gemm_argmin(
    const u16* __restrict__ xh, const u16* __restrict__ ch,
    const float* __restrict__ e2, u32* __restrict__ part) {
  __shared__ __align__(16) u16 lds[LDS_US];
  __shared__ u32 sv1[128], sv2[128];
  const int tid = threadIdx.x;
  const int w = tid >> 6, lane = tid & 63;
  const int fr = lane & 15, qg = lane >> 4;
  const int m0 = blockIdx.x * 128, n0 = blockIdx.y * 128;
  const int m_off = (w & 1) * 64, n_off = (w >> 1) * 64;

  f32x4 acc[4][4];
#pragma unroll
  for (int i = 0; i < 4; ++i)
#pragma unroll
    for (int j = 0; j < 4; ++j) acc[i][j] = (f32x4){0.f, 0.f, 0.f, 0.f};

  const int s0 = w * 128 + lane, s1 = s0 + 64;
  const int r0 = s0 >> 2, g0 = (s0 & 3) ^ ((r0 >> 1) & 3);
  const int r1i = s1 >> 2, g1 = (s1 & 3) ^ ((r1i >> 1) & 3);
  const size_t offA0 = (size_t)(m0 + r0) * CCDIM + g0 * 8;
  const size_t offA1 = (size_t)(m0 + r1i) * CCDIM + g1 * 8;
  const size_t offB0 = (size_t)(n0 + r0) * CCDIM + g0 * 8;
  const size_t offB1 = (size_t)(n0 + r1i) * CCDIM + g1 * 8;
  const int lb0 = (w * 128) * 8, lb1 = lb0 + 512;

#pragma unroll 1
  for (int kt = 0; kt < 8; ++kt) {
    const int c0 = kt * 32;
    GLD(xh + offA0 + c0, &lds[lb0]);
    GLD(xh + offA1 + c0, &lds[lb1]);
    GLD(ch + offB0 + c0, &lds[4096 + lb0]);
    GLD(ch + offB1 + c0, &lds[4096 + lb1]);
    __syncthreads();

    half8 a[4];
#pragma unroll
    for (int mf = 0; mf < 4; ++mf) {
      const int rl = m_off + mf * 16 + fr;
      const int sw = (qg ^ ((rl >> 1) & 3)) * 8;
      a[mf] = *(const half8*)&lds[rl * 32 + sw];
    }
#pragma unroll
    for (int nf = 0; nf < 4; ++nf) {
      const int rl = n_off + nf * 16 + fr;
      const int sw = (qg ^ ((rl >> 1) & 3)) * 8;
      const half8 b = *(const half8*)&lds[4096 + rl * 32 + sw];
#pragma unroll
      for (int mf = 0; mf < 4; ++mf)
        acc[mf][nf] =
            __builtin_amdgcn_mfma_f32_16x16x32_f16(a[mf], b, acc[mf][nf], 0, 0, 0);
    }
    __syncthreads();
  }

  // ---- fold: per (mf,r) row, top-2 over this lane's 4 cols (u32 keys) ----
  u32 cid[4];
  float e2q[4];
#pragma unroll
  for (int nf = 0; nf < 4; ++nf) {
    cid[nf] = n0 + n_off + nf * 16 + fr;
    e2q[nf] = (e2[cid[nf]] + 512.0f) * 256.0f;
  }
  u32 t1[4][4], t2[4][4];
#pragma unroll
  for (int mf = 0; mf < 4; ++mf)
#pragma unroll
    for (int rr = 0; rr < 4; ++rr) {
      const u32 k0 = ((u32)fmaf(acc[mf][0][rr], -512.0f, e2q[0]) << 13) | cid[0];
      const u32 k1 = ((u32)fmaf(acc[mf][1][rr], -512.0f, e2q[1]) << 13) | cid[1];
      const u32 k2 = ((u32)fmaf(acc[mf][2][rr], -512.0f, e2q[2]) << 13) | cid[2];
      const u32 k3 = ((u32)fmaf(acc[mf][3][rr], -512.0f, e2q[3]) << 13) | cid[3];
      const u32 m1 = umin2(k0, k1), x1 = umax2(k0, k1);
      const u32 m2 = umin2(k2, k3), x2 = umax2(k2, k3);
      t1[mf][rr] = umin2(m1, m2);
      t2[mf][rr] = umin2(umax2(m1, m2), umin2(x1, x2));
    }
  // ---- reduce across the 16 lanes (cols) sharing each row ----
#pragma unroll
  for (int mask = 1; mask <= 8; mask <<= 1) {
#pragma unroll
    for (int mf = 0; mf < 4; ++mf)
#pragma unroll
      for (int rr = 0; rr < 4; ++rr) {
        const u32 o1 = (u32)__shfl_xor((int)t1[mf][rr], mask, 64);
        const u32 o2 = (u32)__shfl_xor((int)t2[mf][rr], mask, 64);
        const u32 lo = umin2(t1[mf][rr], o1);
        const u32 hi = umax2(t1[mf][rr], o1);
        t1[mf][rr] = lo;
        t2[mf][rr] = umin2(hi, umin2(t2[mf][rr], o2));
      }
  }
  // ---- combine the two waves sharing rows (n_off 0 vs 64) via LDS ----
  if (fr == 0 && n_off == 64) {
#pragma unroll
    for (int mf = 0; mf < 4; ++mf)
#pragma unroll
      for (int rr = 0; rr < 4; ++rr) {
        const int rl = m_off + mf * 16 + qg * 4 + rr;
        sv1[rl] = t1[mf][rr];
        sv2[rl] = t2[mf][rr];
      }
  }
  __syncthreads();
  if (fr == 0 && n_off == 0) {
#pragma unroll
    for (int mf = 0; mf < 4; ++mf)
#pragma unroll
      for (int rr = 0; rr < 4; ++rr) {
        const int rl = m_off + mf * 16 + qg * 4 + rr;
        const u32 o1 = sv1[rl], o2 = sv2[rl];
        const u32 lo = umin2(t1[mf][rr], o1);
        const u32 hi = umax2(t1[mf][rr], o1);
        part[((size_t)blockIdx.y * 2 + 0) * NPOS + m0 + rl] = lo;
        part[((size_t)blockIdx.y * 2 + 1) * NPOS + m0 + rl] =
            umin2(hi, umin2(t2[mf][rr], o2));
      }
  }
}

// ---------------------------------------------------------------------------
// merge_gather: per 64 positions -- (A) global top-4 candidates from 64x2
// tile keys, (B) exact f32 distance for the 4, pick min (lowest idx ties),
// (C) gather codebook rows -> out [B,C,H,W] + fused sum((q-x)^2).
// ---------------------------------------------------------------------------
__global__ __launch_bounds__(256) void merge_gather(
    const u32* __restrict__ part, const float* __restrict__ x,
    const float* __restrict__ cb, const float* __restrict__ e2,
    float* __restrict__ out, float* __restrict__ accp) {
  __shared__ float rows[64][CCDIM + 1];
  __shared__ u32 ft[64][4];
  __shared__ u32 fi[64];
  __shared__ float wsum[4];
  u32* lt = (u32*)rows;  // overlay: phase-A scratch [256][4]
  u64* bt = (u64*)rows;  // overlay: phase-B scratch [64][4]

  const int tid = threadIdx.x, q = tid >> 6, j = tid & 63;
  const int p0 = blockIdx.x * 64;
  const int m = p0 + j;

  // Phase A: each (q,j) scans 16 tiles x 2 entries -> local sorted top-4
  u32 t1 = ~0u, t2 = ~0u, t3 = ~0u, t4 = ~0u;
#pragma unroll 4
  for (int kb = q * 16; kb < q * 16 + 16; ++kb) {
#pragma unroll
    for (int e = 0; e < 2; ++e) {
      u32 k = part[((size_t)kb * 2 + e) * NPOS + m];
      u32 c = umin2(t1, k);
      k = umax2(t1, k);
      t1 = c;
      c = umin2(t2, k);
      k = umax2(t2, k);
      t2 = c;
      c = umin2(t3, k);
      k = umax2(t3, k);
      t3 = c;
      t4 = umin2(t4, k);
    }
  }
  lt[tid * 4 + 0] = t1;
  lt[tid * 4 + 1] = t2;
  lt[tid * 4 + 2] = t3;
  lt[tid * 4 + 3] = t4;
  __syncthreads();
  if (tid < 64) {
    u32 s1 = ~0u, s2 = ~0u, s3 = ~0u, s4 = ~0u;
#pragma unroll
    for (int qq = 0; qq < 4; ++qq)
#pragma unroll
      for (int e = 0; e < 4; ++e) {
        u32 k = lt[(qq * 64 + tid) * 4 + e];
        u32 c = umin2(s1, k);
        k = umax2(s1, k);
        s1 = c;
        c = umin2(s2, k);
        k = umax2(s2, k);
        s2 = c;
        c = umin2(s3, k);
        k = umax2(s3, k);
        s3 = c;
        s4 = umin2(s4, k);
      }
    ft[tid][0] = s1;
    ft[tid][1] = s2;
    ft[tid][2] = s3;
    ft[tid][3] = s4;
  }
  __syncthreads();

  // Phase B: exact f32 distance for candidate q of position j
  const int ci = (int)(ft[j][q] & 8191u);
  const float* xp = x + (size_t)(m >> 10) * (CCDIM * HWP) + (m & 1023);
  const float* cp = cb + (size_t)ci * CCDIM;
  float dot = 0.f;
#pragma unroll 8
  for (int c = 0; c < CCDIM; ++c) dot = fmaf(xp[(size_t)c * HWP], cp[c], dot);
  const float d = fmaf(-2.0f, dot, e2[ci]);
  const u32 u = __float_as_uint(d);
  const u32 mono = ((int)u < 0) ? ~u : (u | 0x80000000u);
  const u64 k64 = ((u64)mono << 32) | (u32)ci;
  __syncthreads();  // done reading lt region
  bt[j * 4 + q] = k64;
  __syncthreads();
  if (tid < 64) {
    u64 best = bt[tid * 4 + 0];
    if (bt[tid * 4 + 1] < best) best = bt[tid * 4 + 1];
    if (bt[tid * 4 + 2] < best) best = bt[tid * 4 + 2];
    if (bt[tid * 4 + 3] < best) best = bt[tid * 4 + 3];
    fi[tid] = (u32)(best & 8191u);
  }
  __syncthreads();

  // Phase C: gather + loss
  const int lane = tid & 63, wid = tid >> 6;
#pragma unroll 1
  for (int r = wid * 16; r < wid * 16 + 16; ++r) {
    const int code = fi[r];
    const float4 v = *(const float4*)(cb + (size_t)code * CCDIM + lane * 4);
    rows[r][lane * 4 + 0] = v.x;
    rows[r][lane * 4 + 1] = v.y;
    rows[r][lane * 4 + 2] = v.z;
    rows[r][lane * 4 + 3] = v.w;
  }
  __syncthreads();
  const int b = p0 >> 10;
  const int hw0 = p0 & 1023;
  const size_t obase = (size_t)b * (CCDIM * HWP) + hw0 + lane;
  float lsum = 0.0f;
#pragma unroll 4
  for (int c = wid * 64; c < wid * 64 + 64; ++c) {
    const float qv = rows[lane][c];
    const float xv = x[obase + (size_t)c * HWP];
    out[obase + (size_t)c * HWP] = qv;
    const float dd = qv - xv;
    lsum = fmaf(dd, dd, lsum);
  }
#pragma unroll
  for (int off = 32; off > 0; off >>= 1) lsum += __shfl_down(lsum, off, 64);
  if (lane == 0) wsum[wid] = lsum;
  __syncthreads();
  if (tid == 0) atomicAdd(accp, wsum[0] + wsum[1] + wsum[2] + wsum[3]);
}

__global__ void finalize_kernel(const float* __restrict__ acc,
                                float* __restrict__ out) {
  const float mean = acc[0] * (1.0f / (float)((size_t)NPOS * CCDIM));
  out[(size_t)NPOS * CCDIM] = mean;
  out[(size_t)NPOS * CCDIM + 1] = mean;
}

extern "C" void kernel_launch(void* const* d_in, const int* in_sizes, int n_in,
                              void* d_out, int out_size, void* d_ws,
                              size_t ws_size, hipStream_t stream) {
  (void)in_sizes;
  (void)n_in;
  (void)out_size;
  (void)ws_size;
  const float* x = (const float*)d_in[0];
  const float* cb = (const float*)d_in[1];
  float* out = (float*)d_out;

  uint8_t* ws = (uint8_t*)d_ws;
  float* e2 = (float*)(ws + 0);                      // 32 KB
  u32* part = (u32*)(ws + (1ull << 20));             // 8 MB (64*2*NPOS u32)
  u16* xh = (u16*)(ws + (10ull << 20));              // 8 MB
  u16* ch = (u16*)(ws + (20ull << 20));              // 4 MB
  float* acc = (float*)(ws + (25ull << 20));         // 4 B

  hipMemsetAsync(acc, 0, sizeof(float), stream);
  pack_x<<<NPOS / 64, 256, 0, stream>>>(x, xh);
  pack_cb_e2<<<KC / 4, 256, 0, stream>>>(cb, ch, e2);
  gemm_argmin<<<dim3(NPOS / 128, KC / 128), 256, 0, stream>>>(xh, ch, e2, part);
  merge_gather<<<NPOS / 64, 256, 0, stream>>>(part, x, cb, e2, out, acc);
  finalize_kernel<<<1, 1, 0, stream>>>(acc, out);
}

// Round 4
// 205.432 us; speedup vs baseline: 17.9061x; 1.0791x over previous
//
#include <hip/hip_runtime.h>
#include <stdint.h>

// Problem constants (B=16, C=256, H=W=32, K=8192)
#define CCDIM 256
#define HWP 1024
#define NPOS 16384
#define KC 8192
#define NKB 64  // number of 128-code tiles

typedef unsigned short u16;
typedef unsigned int u32;
typedef unsigned long long u64;
typedef __attribute__((ext_vector_type(8))) _Float16 half8;
typedef __attribute__((ext_vector_type(4))) float f32x4;

__device__ __forceinline__ u16 f16bits(float f) {
  _Float16 h = (_Float16)f;  // RNE
  return *(u16*)&h;
}
__device__ __forceinline__ u32 umin2(u32 a, u32 b) { return a < b ? a : b; }
__device__ __forceinline__ u32 umax2(u32 a, u32 b) { return a > b ? a : b; }
__device__ __forceinline__ u64 umin64(u64 a, u64 b) { return a < b ? a : b; }
__device__ __forceinline__ u64 umax64(u64 a, u64 b) { return a > b ? a : b; }
// exact top-2 merge of two sorted pairs (a1<=a2, b1<=b2)
__device__ __forceinline__ void comb(u32& a1, u32& a2, u32 b1, u32 b2) {
  const u32 lo = umin2(a1, b1);
  const u32 hi = umax2(a1, b1);
  a2 = umin2(hi, umin2(a2, b2));
  a1 = lo;
}

// global_load_lds, width 16: lane i -> ldsbase + i*16
#define GLD(g, l)                                                   \
  __builtin_amdgcn_global_load_lds(                                 \
      (const __attribute__((address_space(1))) u32*)(g),            \
      (__attribute__((address_space(3))) u32*)(l), 16, 0, 0)

// ---------------------------------------------------------------------------
// pack_all: blocks [0,2048): cb -> ch (f16) + e2;  blocks [2048,2304):
// x -> xh (f16, transposed to [pos][C]); block 2048 zeroes acc/cnt.
// ---------------------------------------------------------------------------
__global__ __launch_bounds__(256) void pack_all(
    const float* __restrict__ x, const float* __restrict__ cb,
    u16* __restrict__ xh, u16* __restrict__ ch, float* __restrict__ e2,
    float* __restrict__ accp, u32* __restrict__ cntp) {
  __shared__ float tile[64][129];
  const int t = threadIdx.x, lane = t & 63, w = t >> 6;
  if (blockIdx.x < 2048) {
    // ---- codebook pack + e2 ----
    const int k = blockIdx.x * 4 + w;
    const float4 v = *(const float4*)(cb + (size_t)k * CCDIM + lane * 4);
    float s = v.x * v.x + v.y * v.y + v.z * v.z + v.w * v.w;
    const u32 w0 = (u32)f16bits(v.x) | ((u32)f16bits(v.y) << 16);
    const u32 w1 = (u32)f16bits(v.z) | ((u32)f16bits(v.w) << 16);
    *(uint2*)(ch + (size_t)k * CCDIM + lane * 4) = make_uint2(w0, w1);
#pragma unroll
    for (int off = 32; off > 0; off >>= 1) s += __shfl_down(s, off, 64);
    if (lane == 0) e2[k] = s;
    return;
  }
  // ---- x pack (transpose) ----
  const int bid = blockIdx.x - 2048;
  if (bid == 0 && t == 0) {
    accp[0] = 0.0f;
    cntp[0] = 0u;
  }
  const int b = bid >> 4;
  const int hw0 = (bid & 15) * 64;
  const int p0 = bid * 64;  // = b*1024 + hw0
#pragma unroll 1
  for (int half = 0; half < 2; ++half) {
#pragma unroll 4
    for (int i = 0; i < 32; ++i) {
      const int c = half * 128 + w * 32 + i;
      tile[lane][c & 127] =
          x[(size_t)b * (CCDIM * HWP) + (size_t)c * HWP + hw0 + lane];
    }
    __syncthreads();
    const int r = t >> 2, q = t & 3;
#pragma unroll
    for (int j = 0; j < 4; ++j) {
      const int cl0 = (q + 4 * j) * 8;
      u32 wd[4];
#pragma unroll
      for (int p = 0; p < 4; ++p)
        wd[p] = (u32)f16bits(tile[r][cl0 + 2 * p]) |
                ((u32)f16bits(tile[r][cl0 + 2 * p + 1]) << 16);
      *(uint4*)(xh + (size_t)(p0 + r) * CCDIM + half * 128 + cl0) =
          make_uint4(wd[0], wd[1], wd[2], wd[3]);
    }
    __syncthreads();
  }
}

// ---------------------------------------------------------------------------
// gemm_argmin: A = codebook (rows=codes), B = x (cols=positions). 128x128
// tile, BK=32, f16 MFMA. With codes on the output ROW side, each lane holds
// 16 codes x 4 positions -> register-local exact top-2, then 2 shuffle
// rounds (qg) + 1 LDS combine (code-half waves). Keys: float-bit monotone
// (d+1024 > 0), low 7 bits = local code id.
// ---------------------------------------------------------------------------
#define LDS_US (2 * 128 * 32) /* A (ch) + B (xh) tiles, 8 KB each */

__global__ __launch_bounds__(256, 4) void gemm_argmin(
    const u16* __restrict__ xh, const u16* __restrict__ ch,
    const float* __restrict__ e2, u32* __restrict__ part) {
  __shared__ __align__(16) u16 lds[LDS_US];
  __shared__ u32 sv1[128], sv2[128];
  const int tid = threadIdx.x;
  const int w = tid >> 6, lane = tid & 63;
  const int fr = lane & 15, qg = lane >> 4;
  const int p0 = blockIdx.x * 128;  // positions
  const int k0 = blockIdx.y * 128;  // codes
  const int mhalf = (w & 1) * 64;   // code half (A-row offset)
  const int n_off = (w >> 1) * 64;  // position half (B-row offset)

  f32x4 acc[4][4];  // [mf(code tile)][nf(pos tile)]
#pragma unroll
  for (int i = 0; i < 4; ++i)
#pragma unroll
    for (int j = 0; j < 4; ++j) acc[i][j] = (f32x4){0.f, 0.f, 0.f, 0.f};

  const int s0 = w * 128 + lane, s1 = s0 + 64;
  const int r0 = s0 >> 2, g0 = (s0 & 3) ^ ((r0 >> 1) & 3);
  const int r1i = s1 >> 2, g1 = (s1 & 3) ^ ((r1i >> 1) & 3);
  const size_t offA0 = (size_t)(k0 + r0) * CCDIM + g0 * 8;
  const size_t offA1 = (size_t)(k0 + r1i) * CCDIM + g1 * 8;
  const size_t offB0 = (size_t)(p0 + r0) * CCDIM + g0 * 8;
  const size_t offB1 = (size_t)(p0 + r1i) * CCDIM + g1 * 8;
  const int lb0 = (w * 128) * 8, lb1 = lb0 + 512;

#pragma unroll 1
  for (int kt = 0; kt < 8; ++kt) {
    const int c0 = kt * 32;
    GLD(ch + offA0 + c0, &lds[lb0]);
    GLD(ch + offA1 + c0, &lds[lb1]);
    GLD(xh + offB0 + c0, &lds[4096 + lb0]);
    GLD(xh + offB1 + c0, &lds[4096 + lb1]);
    __syncthreads();

    half8 a[4];
#pragma unroll
    for (int mf = 0; mf < 4; ++mf) {
      const int rl = mhalf + mf * 16 + fr;
      const int sw = (qg ^ ((rl >> 1) & 3)) * 8;
      a[mf] = *(const half8*)&lds[rl * 32 + sw];
    }
#pragma unroll
    for (int nf = 0; nf < 4; ++nf) {
      const int rl = n_off + nf * 16 + fr;
      const int sw = (qg ^ ((rl >> 1) & 3)) * 8;
      const half8 b = *(const half8*)&lds[4096 + rl * 32 + sw];
#pragma unroll
      for (int mf = 0; mf < 4; ++mf)
        acc[mf][nf] =
            __builtin_amdgcn_mfma_f32_16x16x32_f16(a[mf], b, acc[mf][nf], 0, 0, 0);
    }
    __syncthreads();
  }

  // ---- epilogue: register-local exact top-2 over this lane's 16 codes ----
  float e2p[16];
  u32 lid[16];
#pragma unroll
  for (int mf = 0; mf < 4; ++mf)
#pragma unroll
    for (int rr = 0; rr < 4; ++rr) {
      const int l = mhalf + mf * 16 + qg * 4 + rr;
      lid[mf * 4 + rr] = (u32)l;
      e2p[mf * 4 + rr] = e2[k0 + l] + 1024.0f;
    }
  u32 t1[4], t2[4];
#pragma unroll
  for (int nf = 0; nf < 4; ++nf) {
    u32 key[16];
#pragma unroll
    for (int mf = 0; mf < 4; ++mf)
#pragma unroll
      for (int rr = 0; rr < 4; ++rr)
        key[mf * 4 + rr] =
            (__float_as_uint(fmaf(acc[mf][nf][rr], -2.0f, e2p[mf * 4 + rr])) &
             0xFFFFFF80u) |
            lid[mf * 4 + rr];
    u32 a1[8], a2[8];
#pragma unroll
    for (int i = 0; i < 8; ++i) {
      a1[i] = umin2(key[2 * i], key[2 * i + 1]);
      a2[i] = umax2(key[2 * i], key[2 * i + 1]);
    }
#pragma unroll
    for (int i = 0; i < 4; ++i) comb(a1[i], a2[i], a1[i + 4], a2[i + 4]);
    comb(a1[0], a2[0], a1[2], a2[2]);
    comb(a1[1], a2[1], a1[3], a2[3]);
    comb(a1[0], a2[0], a1[1], a2[1]);
    t1[nf] = a1[0];
    t2[nf] = a2[0];
  }
  // cross-lane: combine the 4 qg groups (lane bits 4,5)
#pragma unroll
  for (int mask = 16; mask <= 32; mask <<= 1) {
#pragma unroll
    for (int nf = 0; nf < 4; ++nf) {
      const u32 o1 = (u32)__shfl_xor((int)t1[nf], mask, 64);
      const u32 o2 = (u32)__shfl_xor((int)t2[nf], mask, 64);
      comb(t1[nf], t2[nf], o1, o2);
    }
  }
  // combine the two code-half waves sharing positions, then emit
  if (qg == 0 && (w & 1) == 1) {
#pragma unroll
    for (int nf = 0; nf < 4; ++nf) {
      const int pl = n_off + nf * 16 + fr;
      sv1[pl] = t1[nf];
      sv2[pl] = t2[nf];
    }
  }
  __syncthreads();
  if (qg == 0 && (w & 1) == 0) {
#pragma unroll
    for (int nf = 0; nf < 4; ++nf) {
      const int pl = n_off + nf * 16 + fr;
      comb(t1[nf], t2[nf], sv1[pl], sv2[pl]);
      part[((size_t)blockIdx.y * 2 + 0) * NPOS + p0 + pl] = t1[nf];
      part[((size_t)blockIdx.y * 2 + 1) * NPOS + p0 + pl] = t2[nf];
    }
  }
}

// ---------------------------------------------------------------------------
// merge_gather(+finalize): (A) global top-4 from 64x2 tile keys (u64 with
// rebuilt 13-bit global id), (B) exact f32 distance for the 4, pick min,
// (C) gather -> out [B,C,H,W] + fused loss; last block writes both losses.
// ---------------------------------------------------------------------------
__global__ __launch_bounds__(256) void merge_gather(
    const u32* __restrict__ part, const float* __restrict__ x,
    const float* __restrict__ cb, const float* __restrict__ e2,
    float* __restrict__ out, float* __restrict__ accp, u32* __restrict__ cntp) {
  __shared__ float rows[64][CCDIM + 1];
  __shared__ u32 ft[64][4];
  __shared__ u32 fi[64];
  __shared__ float wsum[4];
  u64* lt = (u64*)rows;  // overlay: phase-A scratch [256][4]
  u64* bt = (u64*)rows;  // overlay: phase-B scratch [64][4]

  const int tid = threadIdx.x, q = tid >> 6, j = tid & 63;
  const int p0 = blockIdx.x * 64;
  const int m = p0 + j;

  // Phase A: each (q,j) scans 16 tiles x 2 entries -> sorted top-4 (u64)
  u64 t1 = ~0ull, t2 = ~0ull, t3 = ~0ull, t4 = ~0ull;
#pragma unroll 4
  for (int kb = q * 16; kb < q * 16 + 16; ++kb) {
#pragma unroll
    for (int e = 0; e < 2; ++e) {
      const u32 kk = part[((size_t)kb * 2 + e) * NPOS + m];
      u64 kv = ((u64)(kk & 0xFFFFFF80u) << 32) | (u32)(kb * 128 + (kk & 127u));
      u64 c = umin64(t1, kv);
      kv = umax64(t1, kv);
      t1 = c;
      c = umin64(t2, kv);
      kv = umax64(t2, kv);
      t2 = c;
      c = umin64(t3, kv);
      kv = umax64(t3, kv);
      t3 = c;
      t4 = umin64(t4, kv);
    }
  }
  lt[tid * 4 + 0] = t1;
  lt[tid * 4 + 1] = t2;
  lt[tid * 4 + 2] = t3;
  lt[tid * 4 + 3] = t4;
  __syncthreads();
  if (tid < 64) {
    u64 s1 = ~0ull, s2 = ~0ull, s3 = ~0ull, s4 = ~0ull;
#pragma unroll
    for (int qq = 0; qq < 4; ++qq)
#pragma unroll
      for (int e = 0; e < 4; ++e) {
        u64 k = lt[(qq * 64 + tid) * 4 + e];
        u64 c = umin64(s1, k);
        k = umax64(s1, k);
        s1 = c;
        c = umin64(s2, k);
        k = umax64(s2, k);
        s2 = c;
        c = umin64(s3, k);
        k = umax64(s3, k);
        s3 = c;
        s4 = umin64(s4, k);
      }
    ft[tid][0] = (u32)(s1 & 8191u);
    ft[tid][1] = (u32)(s2 & 8191u);
    ft[tid][2] = (u32)(s3 & 8191u);
    ft[tid][3] = (u32)(s4 & 8191u);
  }
  __syncthreads();

  // Phase B: exact f32 distance for candidate q of position j
  const int ci = (int)ft[j][q];
  const float* xp = x + (size_t)(m >> 10) * (CCDIM * HWP) + (m & 1023);
  const float* cp = cb + (size_t)ci * CCDIM;
  float dot = 0.f;
#pragma unroll 8
  for (int c = 0; c < CCDIM; ++c) dot = fmaf(xp[(size_t)c * HWP], cp[c], dot);
  const float d = fmaf(-2.0f, dot, e2[ci]);
  const u32 u = __float_as_uint(d);
  const u32 mono = ((int)u < 0) ? ~u : (u | 0x80000000u);
  const u64 k64 = ((u64)mono << 32) | (u32)ci;
  bt[j * 4 + q] = k64;
  __syncthreads();
  if (tid < 64) {
    u64 best = bt[tid * 4 + 0];
    best = umin64(best, bt[tid * 4 + 1]);
    best = umin64(best, bt[tid * 4 + 2]);
    best = umin64(best, bt[tid * 4 + 3]);
    fi[tid] = (u32)(best & 8191u);
  }
  __syncthreads();

  // Phase C: gather + loss
  const int lane = tid & 63, wid = tid >> 6;
#pragma unroll 1
  for (int r = wid * 16; r < wid * 16 + 16; ++r) {
    const int code = fi[r];
    const float4 v = *(const float4*)(cb + (size_t)code * CCDIM + lane * 4);
    rows[r][lane * 4 + 0] = v.x;
    rows[r][lane * 4 + 1] = v.y;
    rows[r][lane * 4 + 2] = v.z;
    rows[r][lane * 4 + 3] = v.w;
  }
  __syncthreads();
  const int b = p0 >> 10;
  const int hw0 = p0 & 1023;
  const size_t obase = (size_t)b * (CCDIM * HWP) + hw0 + lane;
  float lsum = 0.0f;
#pragma unroll 4
  for (int c = wid * 64; c < wid * 64 + 64; ++c) {
    const float qv = rows[lane][c];
    const float xv = x[obase + (size_t)c * HWP];
    out[obase + (size_t)c * HWP] = qv;
    const float dd = qv - xv;
    lsum = fmaf(dd, dd, lsum);
  }
#pragma unroll
  for (int off = 32; off > 0; off >>= 1) lsum += __shfl_down(lsum, off, 64);
  if (lane == 0) wsum[wid] = lsum;
  __syncthreads();
  if (tid == 0) {
    atomicAdd(accp, wsum[0] + wsum[1] + wsum[2] + wsum[3]);
    __threadfence();
    const u32 old = atomicAdd(cntp, 1u);
    if (old == gridDim.x - 1) {  // last block: finalize losses
      const float tot = atomicAdd(accp, 0.0f);
      const float mean = tot * (1.0f / (float)((size_t)NPOS * CCDIM));
      out[(size_t)NPOS * CCDIM] = mean;
      out[(size_t)NPOS * CCDIM + 1] = mean;
    }
  }
}

extern "C" void kernel_launch(void* const* d_in, const int* in_sizes, int n_in,
                              void* d_out, int out_size, void* d_ws,
                              size_t ws_size, hipStream_t stream) {
  (void)in_sizes;
  (void)n_in;
  (void)out_size;
  (void)ws_size;
  const float* x = (const float*)d_in[0];
  const float* cb = (const float*)d_in[1];
  float* out = (float*)d_out;

  uint8_t* ws = (uint8_t*)d_ws;
  float* e2 = (float*)(ws + 0);               // 32 KB
  u32* part = (u32*)(ws + (1ull << 20));      // 8 MB (64*2*NPOS u32)
  u16* xh = (u16*)(ws + (10ull << 20));       // 8 MB
  u16* ch = (u16*)(ws + (20ull << 20));       // 4 MB
  float* acc = (float*)(ws + (25ull << 20));  // 4 B
  u32* cnt = (u32*)(ws + (25ull << 20) + 128);

  pack_all<<<2304, 256, 0, stream>>>(x, cb, xh, ch, e2, acc, cnt);
  gemm_argmin<<<dim3(NPOS / 128, KC / 128), 256, 0, stream>>>(xh, ch, e2, part);
  merge_gather<<<NPOS / 64, 256, 0, stream>>>(part, x, cb, e2, out, acc, cnt);
}

// Round 5
// 204.668 us; speedup vs baseline: 17.9729x; 1.0037x over previous
//
#include <hip/hip_runtime.h>
#include <stdint.h>

// Problem constants (B=16, C=256, H=W=32, K=8192)
#define CCDIM 256
#define HWP 1024
#define NPOS 16384
#define KC 8192
#define NKB 64  // number of 128-code tiles

typedef unsigned short u16;
typedef unsigned int u32;
typedef unsigned long long u64;
typedef __attribute__((ext_vector_type(8))) _Float16 half8;
typedef __attribute__((ext_vector_type(4))) float f32x4;

__device__ __forceinline__ u16 f16bits(float f) {
  _Float16 h = (_Float16)f;  // RNE
  return *(u16*)&h;
}
__device__ __forceinline__ u32 umin2(u32 a, u32 b) { return a < b ? a : b; }
__device__ __forceinline__ u32 umax2(u32 a, u32 b) { return a > b ? a : b; }
__device__ __forceinline__ u64 umin64(u64 a, u64 b) { return a < b ? a : b; }
__device__ __forceinline__ u64 umax64(u64 a, u64 b) { return a > b ? a : b; }
// exact top-2 merge of two sorted pairs (a1<=a2, b1<=b2)
__device__ __forceinline__ void comb(u32& a1, u32& a2, u32 b1, u32 b2) {
  const u32 lo = umin2(a1, b1);
  const u32 hi = umax2(a1, b1);
  a2 = umin2(hi, umin2(a2, b2));
  a1 = lo;
}
// sorted top-4 insert (u64)
__device__ __forceinline__ void ins4(u64& s1, u64& s2, u64& s3, u64& s4,
                                     u64 k) {
  u64 c = umin64(s1, k);
  k = umax64(s1, k);
  s1 = c;
  c = umin64(s2, k);
  k = umax64(s2, k);
  s2 = c;
  c = umin64(s3, k);
  k = umax64(s3, k);
  s3 = c;
  s4 = umin64(s4, k);
}

// global_load_lds, width 16: lane i -> ldsbase + i*16
#define GLD(g, l)                                                   \
  __builtin_amdgcn_global_load_lds(                                 \
      (const __attribute__((address_space(1))) u32*)(g),            \
      (__attribute__((address_space(3))) u32*)(l), 16, 0, 0)

// ---------------------------------------------------------------------------
// pack_all: blocks [0,2048): cb -> ch (f16) + e2;  blocks [2048,2304):
// x -> xh (f16, transposed to [pos][C]); block 2048 zeroes acc/cnt.
// ---------------------------------------------------------------------------
__global__ __launch_bounds__(256) void pack_all(
    const float* __restrict__ x, const float* __restrict__ cb,
    u16* __restrict__ xh, u16* __restrict__ ch, float* __restrict__ e2,
    float* __restrict__ accp, u32* __restrict__ cntp) {
  __shared__ float tile[64][129];
  const int t = threadIdx.x, lane = t & 63, w = t >> 6;
  if (blockIdx.x < 2048) {
    // ---- codebook pack + e2 ----
    const int k = blockIdx.x * 4 + w;
    const float4 v = *(const float4*)(cb + (size_t)k * CCDIM + lane * 4);
    float s = v.x * v.x + v.y * v.y + v.z * v.z + v.w * v.w;
    const u32 w0 = (u32)f16bits(v.x) | ((u32)f16bits(v.y) << 16);
    const u32 w1 = (u32)f16bits(v.z) | ((u32)f16bits(v.w) << 16);
    *(uint2*)(ch + (size_t)k * CCDIM + lane * 4) = make_uint2(w0, w1);
#pragma unroll
    for (int off = 32; off > 0; off >>= 1) s += __shfl_down(s, off, 64);
    if (lane == 0) e2[k] = s;
    return;
  }
  // ---- x pack (transpose) ----
  const int bid = blockIdx.x - 2048;
  if (bid == 0 && t == 0) {
    accp[0] = 0.0f;
    cntp[0] = 0u;
  }
  const int b = bid >> 4;
  const int hw0 = (bid & 15) * 64;
  const int p0 = bid * 64;  // = b*1024 + hw0
#pragma unroll 1
  for (int half = 0; half < 2; ++half) {
#pragma unroll 4
    for (int i = 0; i < 32; ++i) {
      const int c = half * 128 + w * 32 + i;
      tile[lane][c & 127] =
          x[(size_t)b * (CCDIM * HWP) + (size_t)c * HWP + hw0 + lane];
    }
    __syncthreads();
    const int r = t >> 2, q = t & 3;
#pragma unroll
    for (int j = 0; j < 4; ++j) {
      const int cl0 = (q + 4 * j) * 8;
      u32 wd[4];
#pragma unroll
      for (int p = 0; p < 4; ++p)
        wd[p] = (u32)f16bits(tile[r][cl0 + 2 * p]) |
                ((u32)f16bits(tile[r][cl0 + 2 * p + 1]) << 16);
      *(uint4*)(xh + (size_t)(p0 + r) * CCDIM + half * 128 + cl0) =
          make_uint4(wd[0], wd[1], wd[2], wd[3]);
    }
    __syncthreads();
  }
}

// ---------------------------------------------------------------------------
// gemm_argmin: A = codebook (rows), B = x (cols). 128x128 tile, BK=64
// (4 K-iters -> half the barriers of BK=32; LDS 32 KB, still 4 blocks/CU).
// Rows are 8 chunks of 8 f16; swizzle phys_chunk = logical ^ (row&7) applied
// on the GLOBAL fetch side (LDS side of global_load_lds must stay
// lane-linear). Epilogue: register-local exact top-2 over 16 codes, 2
// shuffle rounds, LDS combine, one packed u64 store per position.
// ---------------------------------------------------------------------------
#define LDS_US (2 * 128 * 64) /* A (ch) + B (xh) tiles, 16 KB each */

__global__ __launch_bounds__(256, 4) void gemm_argmin(
    const u16* __restrict__ xh, const u16* __restrict__ ch,
    const float* __restrict__ e2, u64* __restrict__ part) {
  __shared__ __align__(16) u16 lds[LDS_US];
  __shared__ u32 sv1[128], sv2[128];
  const int tid = threadIdx.x;
  const int w = tid >> 6, lane = tid & 63;
  const int fr = lane & 15, qg = lane >> 4;
  const int p0 = blockIdx.x * 128;  // positions
  const int k0 = blockIdx.y * 128;  // codes
  const int mhalf = (w & 1) * 64;   // code half (A-row offset)
  const int n_off = (w >> 1) * 64;  // position half (B-row offset)

  f32x4 acc[4][4];  // [mf(code tile)][nf(pos tile)]
#pragma unroll
  for (int i = 0; i < 4; ++i)
#pragma unroll
    for (int j = 0; j < 4; ++j) acc[i][j] = (f32x4){0.f, 0.f, 0.f, 0.f};

  // staging: 1024 slots per tile; slot s -> row s>>3, phys chunk s&7,
  // logical chunk (s&7)^(row&7). Wave covers slots [w*256, w*256+256).
  size_t offA[4], offB[4];
  int ldso[4];
#pragma unroll
  for (int t = 0; t < 4; ++t) {
    const int s = w * 256 + t * 64 + lane;
    const int r = s >> 3;
    const int lc = (s & 7) ^ (r & 7);
    offA[t] = (size_t)(k0 + r) * CCDIM + lc * 8;
    offB[t] = (size_t)(p0 + r) * CCDIM + lc * 8;
    ldso[t] = (w * 256 + t * 64) * 8;  // u16 index (wave-uniform)
  }

#pragma unroll 1
  for (int kt = 0; kt < 4; ++kt) {
    const int c0 = kt * 64;
#pragma unroll
    for (int t = 0; t < 4; ++t) GLD(ch + offA[t] + c0, &lds[ldso[t]]);
#pragma unroll
    for (int t = 0; t < 4; ++t) GLD(xh + offB[t] + c0, &lds[8192 + ldso[t]]);
    __syncthreads();

#pragma unroll
    for (int st = 0; st < 2; ++st) {
      half8 a[4];
#pragma unroll
      for (int mf = 0; mf < 4; ++mf) {
        const int rl = mhalf + mf * 16 + fr;
        const int pc = (st * 4 + qg) ^ (rl & 7);
        a[mf] = *(const half8*)&lds[rl * 64 + pc * 8];
      }
#pragma unroll
      for (int nf = 0; nf < 4; ++nf) {
        const int rl = n_off + nf * 16 + fr;
        const int pc = (st * 4 + qg) ^ (rl & 7);
        const half8 b = *(const half8*)&lds[8192 + rl * 64 + pc * 8];
#pragma unroll
        for (int mf = 0; mf < 4; ++mf)
          acc[mf][nf] = __builtin_amdgcn_mfma_f32_16x16x32_f16(a[mf], b,
                                                               acc[mf][nf], 0,
                                                               0, 0);
      }
    }
    __syncthreads();
  }

  // ---- epilogue: register-local exact top-2 over this lane's 16 codes ----
  float e2p[16];
  u32 lid[16];
#pragma unroll
  for (int mf = 0; mf < 4; ++mf)
#pragma unroll
    for (int rr = 0; rr < 4; ++rr) {
      const int l = mhalf + mf * 16 + qg * 4 + rr;
      lid[mf * 4 + rr] = (u32)l;
      e2p[mf * 4 + rr] = e2[k0 + l] + 1024.0f;
    }
  u32 t1[4], t2[4];
#pragma unroll
  for (int nf = 0; nf < 4; ++nf) {
    u32 key[16];
#pragma unroll
    for (int mf = 0; mf < 4; ++mf)
#pragma unroll
      for (int rr = 0; rr < 4; ++rr)
        key[mf * 4 + rr] =
            (__float_as_uint(fmaf(acc[mf][nf][rr], -2.0f, e2p[mf * 4 + rr])) &
             0xFFFFFF80u) |
            lid[mf * 4 + rr];
    u32 a1[8], a2[8];
#pragma unroll
    for (int i = 0; i < 8; ++i) {
      a1[i] = umin2(key[2 * i], key[2 * i + 1]);
      a2[i] = umax2(key[2 * i], key[2 * i + 1]);
    }
#pragma unroll
    for (int i = 0; i < 4; ++i) comb(a1[i], a2[i], a1[i + 4], a2[i + 4]);
    comb(a1[0], a2[0], a1[2], a2[2]);
    comb(a1[1], a2[1], a1[3], a2[3]);
    comb(a1[0], a2[0], a1[1], a2[1]);
    t1[nf] = a1[0];
    t2[nf] = a2[0];
  }
  // cross-lane: combine the 4 qg groups (lane bits 4,5)
#pragma unroll
  for (int mask = 16; mask <= 32; mask <<= 1) {
#pragma unroll
    for (int nf = 0; nf < 4; ++nf) {
      const u32 o1 = (u32)__shfl_xor((int)t1[nf], mask, 64);
      const u32 o2 = (u32)__shfl_xor((int)t2[nf], mask, 64);
      comb(t1[nf], t2[nf], o1, o2);
    }
  }
  // combine the two code-half waves sharing positions, then emit packed u64
  if (qg == 0 && (w & 1) == 1) {
#pragma unroll
    for (int nf = 0; nf < 4; ++nf) {
      const int pl = n_off + nf * 16 + fr;
      sv1[pl] = t1[nf];
      sv2[pl] = t2[nf];
    }
  }
  __syncthreads();
  if (qg == 0 && (w & 1) == 0) {
#pragma unroll
    for (int nf = 0; nf < 4; ++nf) {
      const int pl = n_off + nf * 16 + fr;
      comb(t1[nf], t2[nf], sv1[pl], sv2[pl]);
      part[(size_t)blockIdx.y * NPOS + p0 + pl] = ((u64)t1[nf] << 32) | t2[nf];
    }
  }
}

// ---------------------------------------------------------------------------
// merge_gather(+finalize): 512 blocks x 32 positions. (A) 8 subs/position
// scan 8 tiles each (packed u64 part) -> top-4/sub -> serial merge to global
// top-4; (B) exact f32 distance for the 4 (one thread each); (C) gather ->
// out [B,C,H,W] + fused loss; last block writes both losses.
// ---------------------------------------------------------------------------
__global__ __launch_bounds__(256) void merge_gather(
    const u64* __restrict__ part, const float* __restrict__ x,
    const float* __restrict__ cb, const float* __restrict__ e2,
    float* __restrict__ out, float* __restrict__ accp, u32* __restrict__ cntp) {
  __shared__ float rows[32][CCDIM + 1];
  __shared__ u32 ft[32][4];
  __shared__ u32 fi[32];
  __shared__ float wsum[4];
  u64* lt = (u64*)rows;  // overlay: phase-A scratch [32][8][4] u64 (8 KB)
  u64* bt = (u64*)rows;  // overlay: phase-B scratch [32][4] u64 (1 KB)

  const int tid = threadIdx.x;
  const int p0 = blockIdx.x * 32;

  // Phase A1: sub scans 8 tiles (16 entries) -> sorted top-4 (u64 global id)
  {
    const int sub = tid & 7, p = tid >> 3;  // 8 subs x 32 positions
    const int m = p0 + p;
    u64 s1 = ~0ull, s2 = ~0ull, s3 = ~0ull, s4 = ~0ull;
#pragma unroll 2
    for (int kb = sub * 8; kb < sub * 8 + 8; ++kb) {
      const u64 v = part[(size_t)kb * NPOS + m];
      const u32 k1 = (u32)(v >> 32), k2 = (u32)v;
      ins4(s1, s2, s3, s4,
           ((u64)(k1 & 0xFFFFFF80u) << 32) | (u32)(kb * 128 + (k1 & 127u)));
      ins4(s1, s2, s3, s4,
           ((u64)(k2 & 0xFFFFFF80u) << 32) | (u32)(kb * 128 + (k2 & 127u)));
    }
    lt[(p * 8 + sub) * 4 + 0] = s1;
    lt[(p * 8 + sub) * 4 + 1] = s2;
    lt[(p * 8 + sub) * 4 + 2] = s3;
    lt[(p * 8 + sub) * 4 + 3] = s4;
  }
  __syncthreads();
  // Phase A2: one thread per position merges 8x4 -> global top-4
  if (tid < 32) {
    u64 s1 = ~0ull, s2 = ~0ull, s3 = ~0ull, s4 = ~0ull;
#pragma unroll 1
    for (int ssub = 0; ssub < 8; ++ssub)
#pragma unroll
      for (int e = 0; e < 4; ++e)
        ins4(s1, s2, s3, s4, lt[(tid * 8 + ssub) * 4 + e]);
    ft[tid][0] = (u32)(s1 & 8191u);
    ft[tid][1] = (u32)(s2 & 8191u);
    ft[tid][2] = (u32)(s3 & 8191u);
    ft[tid][3] = (u32)(s4 & 8191u);
  }
  __syncthreads();

  // Phase B: exact f32 distance for candidate q of position p
  if (tid < 128) {
    const int p = tid >> 2, q = tid & 3;
    const int m = p0 + p;
    const int ci = (int)ft[p][q];
    const float* xp = x + (size_t)(m >> 10) * (CCDIM * HWP) + (m & 1023);
    const float* cp = cb + (size_t)ci * CCDIM;
    float dot = 0.f;
#pragma unroll 8
    for (int c = 0; c < CCDIM; ++c) dot = fmaf(xp[(size_t)c * HWP], cp[c], dot);
    const float d = fmaf(-2.0f, dot, e2[ci]);
    const u32 u = __float_as_uint(d);
    const u32 mono = ((int)u < 0) ? ~u : (u | 0x80000000u);
    bt[p * 4 + q] = ((u64)mono << 32) | (u32)ci;
  }
  __syncthreads();
  if (tid < 32) {
    u64 best = bt[tid * 4 + 0];
    best = umin64(best, bt[tid * 4 + 1]);
    best = umin64(best, bt[tid * 4 + 2]);
    best = umin64(best, bt[tid * 4 + 3]);
    fi[tid] = (u32)(best & 8191u);
  }
  __syncthreads();

  // Phase C: gather 32 rows (8 threads x 32 floats each), then write out
  {
    const int r = tid >> 3, sseg = tid & 7;
    const int code = fi[r];
#pragma unroll
    for (int j = 0; j < 8; ++j) {
      const float4 v =
          *(const float4*)(cb + (size_t)code * CCDIM + sseg * 32 + j * 4);
      rows[r][sseg * 32 + j * 4 + 0] = v.x;
      rows[r][sseg * 32 + j * 4 + 1] = v.y;
      rows[r][sseg * 32 + j * 4 + 2] = v.z;
      rows[r][sseg * 32 + j * 4 + 3] = v.w;
    }
  }
  __syncthreads();
  const int b = p0 >> 10;
  const int hw0 = p0 & 1023;
  const int hwoff = tid & 31, cg = tid >> 5;  // 8 c-groups of 32
  const size_t obase = (size_t)b * (CCDIM * HWP) + hw0 + hwoff;
  float lsum = 0.0f;
#pragma unroll 4
  for (int i = 0; i < 32; ++i) {
    const int c = cg * 32 + i;
    const float qv = rows[hwoff][c];
    const float xv = x[obase + (size_t)c * HWP];
    out[obase + (size_t)c * HWP] = qv;
    const float dd = qv - xv;
    lsum = fmaf(dd, dd, lsum);
  }
#pragma unroll
  for (int off = 32; off > 0; off >>= 1) lsum += __shfl_down(lsum, off, 64);
  if ((tid & 63) == 0) wsum[tid >> 6] = lsum;
  __syncthreads();
  if (tid == 0) {
    atomicAdd(accp, wsum[0] + wsum[1] + wsum[2] + wsum[3]);
    __threadfence();
    const u32 old = atomicAdd(cntp, 1u);
    if (old == gridDim.x - 1) {  // last block: finalize losses
      const float tot = atomicAdd(accp, 0.0f);
      const float mean = tot * (1.0f / (float)((size_t)NPOS * CCDIM));
      out[(size_t)NPOS * CCDIM] = mean;
      out[(size_t)NPOS * CCDIM + 1] = mean;
    }
  }
}

extern "C" void kernel_launch(void* const* d_in, const int* in_sizes, int n_in,
                              void* d_out, int out_size, void* d_ws,
                              size_t ws_size, hipStream_t stream) {
  (void)in_sizes;
  (void)n_in;
  (void)out_size;
  (void)ws_size;
  const float* x = (const float*)d_in[0];
  const float* cb = (const float*)d_in[1];
  float* out = (float*)d_out;

  uint8_t* ws = (uint8_t*)d_ws;
  float* e2 = (float*)(ws + 0);               // 32 KB
  u64* part = (u64*)(ws + (1ull << 20));      // 8.4 MB (64*NPOS u64)
  u16* xh = (u16*)(ws + (10ull << 20));       // 8.4 MB
  u16* ch = (u16*)(ws + (20ull << 20));       // 4.2 MB
  float* acc = (float*)(ws + (25ull << 20));  // 4 B
  u32* cnt = (u32*)(ws + (25ull << 20) + 128);

  pack_all<<<2304, 256, 0, stream>>>(x, cb, xh, ch, e2, acc, cnt);
  gemm_argmin<<<dim3(NPOS / 128, KC / 128), 256, 0, stream>>>(xh, ch, e2, part);
  merge_gather<<<NPOS / 32, 256, 0, stream>>>(part, x, cb, e2, out, acc, cnt);
}

// Round 6
// 188.509 us; speedup vs baseline: 19.5135x; 1.0857x over previous
//
#include <hip/hip_runtime.h>
#include <stdint.h>

// Problem constants (B=16, C=256, H=W=32, K=8192)
#define CCDIM 256
#define HWP 1024
#define NPOS 16384
#define KC 8192
#define NKB 64  // number of 128-code tiles

typedef unsigned short u16;
typedef unsigned int u32;
typedef unsigned long long u64;
typedef __attribute__((ext_vector_type(8))) _Float16 half8;
typedef __attribute__((ext_vector_type(4))) float f32x4;

__device__ __forceinline__ u16 f16bits(float f) {
  _Float16 h = (_Float16)f;  // RNE
  return *(u16*)&h;
}
__device__ __forceinline__ u32 umin2(u32 a, u32 b) { return a < b ? a : b; }
__device__ __forceinline__ u32 umax2(u32 a, u32 b) { return a > b ? a : b; }
__device__ __forceinline__ u64 umin64(u64 a, u64 b) { return a < b ? a : b; }
__device__ __forceinline__ u64 umax64(u64 a, u64 b) { return a > b ? a : b; }
// exact top-2 merge of two sorted pairs (a1<=a2, b1<=b2)
__device__ __forceinline__ void comb(u32& a1, u32& a2, u32 b1, u32 b2) {
  const u32 lo = umin2(a1, b1);
  const u32 hi = umax2(a1, b1);
  a2 = umin2(hi, umin2(a2, b2));
  a1 = lo;
}
// sorted top-4 insert (u64)
__device__ __forceinline__ void ins4(u64& s1, u64& s2, u64& s3, u64& s4,
                                     u64 k) {
  u64 c = umin64(s1, k);
  k = umax64(s1, k);
  s1 = c;
  c = umin64(s2, k);
  k = umax64(s2, k);
  s2 = c;
  c = umin64(s3, k);
  k = umax64(s3, k);
  s3 = c;
  s4 = umin64(s4, k);
}

// global_load_lds, width 16: lane i -> ldsbase + i*16
#define GLD(g, l)                                                   \
  __builtin_amdgcn_global_load_lds(                                 \
      (const __attribute__((address_space(1))) u32*)(g),            \
      (__attribute__((address_space(3))) u32*)(l), 16, 0, 0)

// ---------------------------------------------------------------------------
// pack_all: blocks [0,2048): cb -> ch (f16) + e2;  blocks [2048,2304):
// x -> xh (f16, transposed to [pos][C]); block 2048 zeroes acc/cnt.
// ---------------------------------------------------------------------------
__global__ __launch_bounds__(256) void pack_all(
    const float* __restrict__ x, const float* __restrict__ cb,
    u16* __restrict__ xh, u16* __restrict__ ch, float* __restrict__ e2,
    float* __restrict__ accp, u32* __restrict__ cntp) {
  __shared__ float tile[64][129];
  const int t = threadIdx.x, lane = t & 63, w = t >> 6;
  if (blockIdx.x < 2048) {
    // ---- codebook pack + e2 ----
    const int k = blockIdx.x * 4 + w;
    const float4 v = *(const float4*)(cb + (size_t)k * CCDIM + lane * 4);
    float s = v.x * v.x + v.y * v.y + v.z * v.z + v.w * v.w;
    const u32 w0 = (u32)f16bits(v.x) | ((u32)f16bits(v.y) << 16);
    const u32 w1 = (u32)f16bits(v.z) | ((u32)f16bits(v.w) << 16);
    *(uint2*)(ch + (size_t)k * CCDIM + lane * 4) = make_uint2(w0, w1);
#pragma unroll
    for (int off = 32; off > 0; off >>= 1) s += __shfl_down(s, off, 64);
    if (lane == 0) e2[k] = s;
    return;
  }
  // ---- x pack (transpose) ----
  const int bid = blockIdx.x - 2048;
  if (bid == 0 && t == 0) {
    accp[0] = 0.0f;
    cntp[0] = 0u;
  }
  const int b = bid >> 4;
  const int hw0 = (bid & 15) * 64;
  const int p0 = bid * 64;  // = b*1024 + hw0
#pragma unroll 1
  for (int half = 0; half < 2; ++half) {
#pragma unroll 4
    for (int i = 0; i < 32; ++i) {
      const int c = half * 128 + w * 32 + i;
      tile[lane][c & 127] =
          x[(size_t)b * (CCDIM * HWP) + (size_t)c * HWP + hw0 + lane];
    }
    __syncthreads();
    const int r = t >> 2, q = t & 3;
#pragma unroll
    for (int j = 0; j < 4; ++j) {
      const int cl0 = (q + 4 * j) * 8;
      u32 wd[4];
#pragma unroll
      for (int p = 0; p < 4; ++p)
        wd[p] = (u32)f16bits(tile[r][cl0 + 2 * p]) |
                ((u32)f16bits(tile[r][cl0 + 2 * p + 1]) << 16);
      *(uint4*)(xh + (size_t)(p0 + r) * CCDIM + half * 128 + cl0) =
          make_uint4(wd[0], wd[1], wd[2], wd[3]);
    }
    __syncthreads();
  }
}

// ---------------------------------------------------------------------------
// gemm_argmin: UNCHANGED from R5 (control). A = codebook, B = x, 128x128,
// BK=64, f16 MFMA, register-local top-2 epilogue, packed u64 partials.
// ---------------------------------------------------------------------------
#define LDS_US (2 * 128 * 64) /* A (ch) + B (xh) tiles, 16 KB each */

__global__ __launch_bounds__(256, 4) void gemm_argmin(
    const u16* __restrict__ xh, const u16* __restrict__ ch,
    const float* __restrict__ e2, u64* __restrict__ part) {
  __shared__ __align__(16) u16 lds[LDS_US];
  __shared__ u32 sv1[128], sv2[128];
  const int tid = threadIdx.x;
  const int w = tid >> 6, lane = tid & 63;
  const int fr = lane & 15, qg = lane >> 4;
  const int p0 = blockIdx.x * 128;  // positions
  const int k0 = blockIdx.y * 128;  // codes
  const int mhalf = (w & 1) * 64;   // code half (A-row offset)
  const int n_off = (w >> 1) * 64;  // position half (B-row offset)

  f32x4 acc[4][4];  // [mf(code tile)][nf(pos tile)]
#pragma unroll
  for (int i = 0; i < 4; ++i)
#pragma unroll
    for (int j = 0; j < 4; ++j) acc[i][j] = (f32x4){0.f, 0.f, 0.f, 0.f};

  size_t offA[4], offB[4];
  int ldso[4];
#pragma unroll
  for (int t = 0; t < 4; ++t) {
    const int s = w * 256 + t * 64 + lane;
    const int r = s >> 3;
    const int lc = (s & 7) ^ (r & 7);
    offA[t] = (size_t)(k0 + r) * CCDIM + lc * 8;
    offB[t] = (size_t)(p0 + r) * CCDIM + lc * 8;
    ldso[t] = (w * 256 + t * 64) * 8;  // u16 index (wave-uniform)
  }

#pragma unroll 1
  for (int kt = 0; kt < 4; ++kt) {
    const int c0 = kt * 64;
#pragma unroll
    for (int t = 0; t < 4; ++t) GLD(ch + offA[t] + c0, &lds[ldso[t]]);
#pragma unroll
    for (int t = 0; t < 4; ++t) GLD(xh + offB[t] + c0, &lds[8192 + ldso[t]]);
    __syncthreads();

#pragma unroll
    for (int st = 0; st < 2; ++st) {
      half8 a[4];
#pragma unroll
      for (int mf = 0; mf < 4; ++mf) {
        const int rl = mhalf + mf * 16 + fr;
        const int pc = (st * 4 + qg) ^ (rl & 7);
        a[mf] = *(const half8*)&lds[rl * 64 + pc * 8];
      }
#pragma unroll
      for (int nf = 0; nf < 4; ++nf) {
        const int rl = n_off + nf * 16 + fr;
        const int pc = (st * 4 + qg) ^ (rl & 7);
        const half8 b = *(const half8*)&lds[8192 + rl * 64 + pc * 8];
#pragma unroll
        for (int mf = 0; mf < 4; ++mf)
          acc[mf][nf] = __builtin_amdgcn_mfma_f32_16x16x32_f16(a[mf], b,
                                                               acc[mf][nf], 0,
                                                               0, 0);
      }
    }
    __syncthreads();
  }

  float e2p[16];
  u32 lid[16];
#pragma unroll
  for (int mf = 0; mf < 4; ++mf)
#pragma unroll
    for (int rr = 0; rr < 4; ++rr) {
      const int l = mhalf + mf * 16 + qg * 4 + rr;
      lid[mf * 4 + rr] = (u32)l;
      e2p[mf * 4 + rr] = e2[k0 + l] + 1024.0f;
    }
  u32 t1[4], t2[4];
#pragma unroll
  for (int nf = 0; nf < 4; ++nf) {
    u32 key[16];
#pragma unroll
    for (int mf = 0; mf < 4; ++mf)
#pragma unroll
      for (int rr = 0; rr < 4; ++rr)
        key[mf * 4 + rr] =
            (__float_as_uint(fmaf(acc[mf][nf][rr], -2.0f, e2p[mf * 4 + rr])) &
             0xFFFFFF80u) |
            lid[mf * 4 + rr];
    u32 a1[8], a2[8];
#pragma unroll
    for (int i = 0; i < 8; ++i) {
      a1[i] = umin2(key[2 * i], key[2 * i + 1]);
      a2[i] = umax2(key[2 * i], key[2 * i + 1]);
    }
#pragma unroll
    for (int i = 0; i < 4; ++i) comb(a1[i], a2[i], a1[i + 4], a2[i + 4]);
    comb(a1[0], a2[0], a1[2], a2[2]);
    comb(a1[1], a2[1], a1[3], a2[3]);
    comb(a1[0], a2[0], a1[1], a2[1]);
    t1[nf] = a1[0];
    t2[nf] = a2[0];
  }
#pragma unroll
  for (int mask = 16; mask <= 32; mask <<= 1) {
#pragma unroll
    for (int nf = 0; nf < 4; ++nf) {
      const u32 o1 = (u32)__shfl_xor((int)t1[nf], mask, 64);
      const u32 o2 = (u32)__shfl_xor((int)t2[nf], mask, 64);
      comb(t1[nf], t2[nf], o1, o2);
    }
  }
  if (qg == 0 && (w & 1) == 1) {
#pragma unroll
    for (int nf = 0; nf < 4; ++nf) {
      const int pl = n_off + nf * 16 + fr;
      sv1[pl] = t1[nf];
      sv2[pl] = t2[nf];
    }
  }
  __syncthreads();
  if (qg == 0 && (w & 1) == 0) {
#pragma unroll
    for (int nf = 0; nf < 4; ++nf) {
      const int pl = n_off + nf * 16 + fr;
      comb(t1[nf], t2[nf], sv1[pl], sv2[pl]);
      part[(size_t)blockIdx.y * NPOS + p0 + pl] = ((u64)t1[nf] << 32) | t2[nf];
    }
  }
}

// ---------------------------------------------------------------------------
// merge_gather(+finalize), REWRITTEN: 512 blocks x 32 positions.
// x-tile staged ONCE coalesced into LDS [32][257] (odd stride: column access
// conflict-free). Phase A: candidate top-4 (u64 keys). Phase B: exact f32
// dots from LDS x + L2-resident cb rows, 8 threads/position, shfl merge.
// Phase C: gather winner rows, fused loss, substitute q into the x-tile in
// place, then coalesced transposed write-out. Last block writes losses.
// ---------------------------------------------------------------------------
__global__ __launch_bounds__(256, 4) void merge_gather(
    const u64* __restrict__ part, const float* __restrict__ x,
    const float* __restrict__ cb, const float* __restrict__ e2,
    float* __restrict__ out, float* __restrict__ accp, u32* __restrict__ cntp) {
  __shared__ float xt[32][CCDIM + 1];  // 32.1 KB: x tile, then q tile
  __shared__ u32 ft[32][4];
  __shared__ u32 fi[32];
  __shared__ float wsum[4];
  u64* lt = (u64*)xt;  // overlay: phase-A scratch [32][8][4] u64 (8 KB)

  const int tid = threadIdx.x;
  const int p0 = blockIdx.x * 32;
  const int b = p0 >> 10;
  const int hw0 = p0 & 1023;

  // ---- Phase A1: 8 subs/position scan 8 tiles each -> sorted top-4 ----
  {
    const int p = tid & 31, sub = tid >> 5;  // coalesced part reads
    const int m = p0 + p;
    u64 s1 = ~0ull, s2 = ~0ull, s3 = ~0ull, s4 = ~0ull;
#pragma unroll 2
    for (int kb = sub * 8; kb < sub * 8 + 8; ++kb) {
      const u64 v = part[(size_t)kb * NPOS + m];
      const u32 k1 = (u32)(v >> 32), k2 = (u32)v;
      ins4(s1, s2, s3, s4,
           ((u64)(k1 & 0xFFFFFF80u) << 32) | (u32)(kb * 128 + (k1 & 127u)));
      ins4(s1, s2, s3, s4,
           ((u64)(k2 & 0xFFFFFF80u) << 32) | (u32)(kb * 128 + (k2 & 127u)));
    }
    lt[(p * 8 + sub) * 4 + 0] = s1;
    lt[(p * 8 + sub) * 4 + 1] = s2;
    lt[(p * 8 + sub) * 4 + 2] = s3;
    lt[(p * 8 + sub) * 4 + 3] = s4;
  }
  __syncthreads();
  // ---- Phase A2: one thread per position merges 8x4 -> global top-4 ----
  if (tid < 32) {
    u64 s1 = ~0ull, s2 = ~0ull, s3 = ~0ull, s4 = ~0ull;
#pragma unroll 1
    for (int ssub = 0; ssub < 8; ++ssub)
#pragma unroll
      for (int e = 0; e < 4; ++e)
        ins4(s1, s2, s3, s4, lt[(tid * 8 + ssub) * 4 + e]);
    ft[tid][0] = (u32)(s1 & 8191u);
    ft[tid][1] = (u32)(s2 & 8191u);
    ft[tid][2] = (u32)(s3 & 8191u);
    ft[tid][3] = (u32)(s4 & 8191u);
  }
  __syncthreads();  // lt reads done; xt reuse is now safe

  // ---- stage x tile (coalesced 128 B segments) ----
  {
    const int hwoff = tid & 31, cg = tid >> 5;
    const size_t xbase = (size_t)b * (CCDIM * HWP) + hw0 + hwoff;
#pragma unroll 8
    for (int i = 0; i < 32; ++i) {
      const int c = cg * 32 + i;
      xt[hwoff][c] = x[xbase + (size_t)c * HWP];
    }
  }
  __syncthreads();

  // ---- Phase B: exact f32 dots; 8 threads per position ----
  {
    const int p = tid >> 3, s = tid & 7;  // q = s>>1, half = s&1
    const int ci = (int)ft[p][s >> 1];
    const float* cp = cb + (size_t)ci * CCDIM + (s & 1) * 128;
    const float* xr = &xt[p][(s & 1) * 128];
    float d0 = 0.f, d1 = 0.f;
#pragma unroll
    for (int j = 0; j < 16; ++j) {
      const float4 v = *(const float4*)(cp + j * 8);
      const float4 v2 = *(const float4*)(cp + j * 8 + 4);
      d0 = fmaf(v.x, xr[j * 8 + 0], d0);
      d0 = fmaf(v.y, xr[j * 8 + 1], d0);
      d0 = fmaf(v.z, xr[j * 8 + 2], d0);
      d0 = fmaf(v.w, xr[j * 8 + 3], d0);
      d1 = fmaf(v2.x, xr[j * 8 + 4], d1);
      d1 = fmaf(v2.y, xr[j * 8 + 5], d1);
      d1 = fmaf(v2.z, xr[j * 8 + 6], d1);
      d1 = fmaf(v2.w, xr[j * 8 + 7], d1);
    }
    float dot = d0 + d1;
    dot += __shfl_xor(dot, 1, 64);  // combine C-halves
    const float d = fmaf(-2.0f, dot, e2[ci]);
    const u32 u = __float_as_uint(d);
    const u32 mono = ((int)u < 0) ? ~u : (u | 0x80000000u);
    u64 key = ((u64)mono << 32) | (u32)ci;
    key = umin64(key, (u64)__shfl_xor((long long)key, 2, 64));
    key = umin64(key, (u64)__shfl_xor((long long)key, 4, 64));
    if (s == 0) fi[p] = (u32)(key & 8191u);
  }
  __syncthreads();

  // ---- Phase C: gather winners + loss + in-place substitute ----
  float lsum = 0.0f;
  {
    const int r = tid & 31, seg = tid >> 5;  // conflict-free LDS (r varies)
    const int code = (int)fi[r];
    const float* cp = cb + (size_t)code * CCDIM + seg * 32;
#pragma unroll
    for (int j = 0; j < 8; ++j) {
      const float4 v = *(const float4*)(cp + j * 4);
      const int c = seg * 32 + j * 4;
      float dd;
      dd = v.x - xt[r][c + 0]; lsum = fmaf(dd, dd, lsum); xt[r][c + 0] = v.x;
      dd = v.y - xt[r][c + 1]; lsum = fmaf(dd, dd, lsum); xt[r][c + 1] = v.y;
      dd = v.z - xt[r][c + 2]; lsum = fmaf(dd, dd, lsum); xt[r][c + 2] = v.z;
      dd = v.w - xt[r][c + 3]; lsum = fmaf(dd, dd, lsum); xt[r][c + 3] = v.w;
    }
  }
  __syncthreads();

  // ---- write out (coalesced 128 B segments) ----
  {
    const int hwoff = tid & 31, cg = tid >> 5;
    const size_t obase = (size_t)b * (CCDIM * HWP) + hw0 + hwoff;
#pragma unroll 8
    for (int i = 0; i < 32; ++i) {
      const int c = cg * 32 + i;
      out[obase + (size_t)c * HWP] = xt[hwoff][c];
    }
  }

  // ---- loss reduction + last-block finalize ----
#pragma unroll
  for (int off = 32; off > 0; off >>= 1) lsum += __shfl_down(lsum, off, 64);
  if ((tid & 63) == 0) wsum[tid >> 6] = lsum;
  __syncthreads();
  if (tid == 0) {
    atomicAdd(accp, wsum[0] + wsum[1] + wsum[2] + wsum[3]);
    __threadfence();
    const u32 old = atomicAdd(cntp, 1u);
    if (old == gridDim.x - 1) {  // last block: finalize losses
      const float tot = atomicAdd(accp, 0.0f);
      const float mean = tot * (1.0f / (float)((size_t)NPOS * CCDIM));
      out[(size_t)NPOS * CCDIM] = mean;
      out[(size_t)NPOS * CCDIM + 1] = mean;
    }
  }
}

extern "C" void kernel_launch(void* const* d_in, const int* in_sizes, int n_in,
                              void* d_out, int out_size, void* d_ws,
                              size_t ws_size, hipStream_t stream) {
  (void)in_sizes;
  (void)n_in;
  (void)out_size;
  (void)ws_size;
  const float* x = (const float*)d_in[0];
  const float* cb = (const float*)d_in[1];
  float* out = (float*)d_out;

  uint8_t* ws = (uint8_t*)d_ws;
  float* e2 = (float*)(ws + 0);               // 32 KB
  u64* part = (u64*)(ws + (1ull << 20));      // 8.4 MB (64*NPOS u64)
  u16* xh = (u16*)(ws + (10ull << 20));       // 8.4 MB
  u16* ch = (u16*)(ws + (20ull << 20));       // 4.2 MB
  float* acc = (float*)(ws + (25ull << 20));  // 4 B
  u32* cnt = (u32*)(ws + (25ull << 20) + 128);

  pack_all<<<2304, 256, 0, stream>>>(x, cb, xh, ch, e2, acc, cnt);
  gemm_argmin<<<dim3(NPOS / 128, KC / 128), 256, 0, stream>>>(xh, ch, e2, part);
  merge_gather<<<NPOS / 32, 256, 0, stream>>>(part, x, cb, e2, out, acc, cnt);
}